// Round 1
// baseline (1939.662 us; speedup 1.0000x reference)
//
#include <hip/hip_runtime.h>
#include <math.h>

#define NTOK 2304   // N = 48*48
#define DIMC 256

// ---------------------------------------------------------------------------
// K1: fused GEMM  Y[9216,1024] = X[9216,256] @ [wq;wkv;wres]^T, scatter epilogue
// 128x128 tile, 256 threads, 8x8 microtile, K chunks of 16
// ---------------------------------------------------------------------------
__global__ __launch_bounds__(256) void k_gemm_qkvres(
    const float* __restrict__ x, const float* __restrict__ wq,
    const float* __restrict__ wkv, const float* __restrict__ wres,
    float* __restrict__ qb, float* __restrict__ kb,
    float* __restrict__ vb, float* __restrict__ resb) {
  __shared__ __align__(16) float xs[128][20];
  __shared__ __align__(16) float ws[128][20];
  const int tid = threadIdx.x;
  const int ty = tid >> 4, tx = tid & 15;
  const int row0 = blockIdx.x * 128;
  const int col0 = blockIdx.y * 128;
  const float* wbase; int wr0;
  if (col0 < 256)      { wbase = wq;   wr0 = col0; }
  else if (col0 < 768) { wbase = wkv;  wr0 = col0 - 256; }
  else                 { wbase = wres; wr0 = col0 - 768; }

  float acc[8][8];
#pragma unroll
  for (int i = 0; i < 8; ++i)
#pragma unroll
    for (int j = 0; j < 8; ++j) acc[i][j] = 0.f;

  for (int kc = 0; kc < 256; kc += 16) {
#pragma unroll
    for (int l = 0; l < 2; ++l) {
      int lin = tid + l * 256;          // 0..511
      int r = lin >> 2;                 // 0..127
      int kk = (lin & 3) * 4;
      *(float4*)&xs[r][kk] = *(const float4*)&x[(size_t)(row0 + r) * 256 + kc + kk];
      *(float4*)&ws[r][kk] = *(const float4*)&wbase[(size_t)(wr0 + r) * 256 + kc + kk];
    }
    __syncthreads();
#pragma unroll
    for (int k4 = 0; k4 < 4; ++k4) {
      float4 a4[8], b4[8];
#pragma unroll
      for (int i = 0; i < 8; ++i) a4[i] = *(float4*)&xs[ty + 16 * i][k4 * 4];
#pragma unroll
      for (int j = 0; j < 8; ++j) b4[j] = *(float4*)&ws[tx + 16 * j][k4 * 4];
#pragma unroll
      for (int i = 0; i < 8; ++i)
#pragma unroll
        for (int j = 0; j < 8; ++j)
          acc[i][j] += a4[i].x * b4[j].x + a4[i].y * b4[j].y +
                       a4[i].z * b4[j].z + a4[i].w * b4[j].w;
    }
    __syncthreads();
  }

#pragma unroll
  for (int i = 0; i < 8; ++i) {
    int row = row0 + ty + 16 * i;
    int b = row / NTOK;
    int n = row % NTOK;
#pragma unroll
    for (int j = 0; j < 8; ++j) {
      int col = col0 + tx + 16 * j;
      float vv = acc[i][j];
      if (col < 256) {
        int head = col >> 5, ch = col & 31;
        qb[(((size_t)b * 8 + head) * NTOK + n) * 32 + ch] = vv;
      } else if (col < 512) {
        int o = col - 256; int head = o >> 5, ch = o & 31;
        kb[(((size_t)b * 8 + head) * NTOK + n) * 32 + ch] = vv;
      } else if (col < 768) {
        int o = col - 512; int head = o >> 5, ch = o & 31;
        vb[(((size_t)b * 8 + head) * NTOK + n) * 32 + ch] = vv;
      } else {
        int c = col - 768;
        resb[((size_t)b * 256 + c) * NTOK + n] = fmaxf(vv, 0.f);
      }
    }
  }
}

// ---------------------------------------------------------------------------
// K2: flash attention per (b,h). 64-row q tile, 64-col k/v tiles, fp32.
// ---------------------------------------------------------------------------
__global__ __launch_bounds__(256) void k_attn(
    const float* __restrict__ qb, const float* __restrict__ kb,
    const float* __restrict__ vb, float* __restrict__ ob) {
  const int bh = blockIdx.y;           // 0..31
  const int r0 = blockIdx.x * 64;
  const int tid = threadIdx.x;
  const int ty = tid >> 4, tx = tid & 15;
  __shared__ __align__(16) float qs[64][36];
  __shared__ __align__(16) float ks[64][36];
  __shared__ __align__(16) float Vt[32][68];
  __shared__ __align__(16) float Ps[64][68];
  __shared__ float m_s[64], l_s[64], sc_s[64];
  const float scale = 0.17677669529663688f;   // 32^-0.5

  const float* qptr = qb + ((size_t)bh * NTOK + r0) * 32;
#pragma unroll
  for (int l = 0; l < 2; ++l) {
    int lin = tid + l * 256;
    int r = lin >> 3, c4 = (lin & 7) * 4;
    float4 t4 = *(const float4*)&qptr[r * 32 + c4];
    t4.x *= scale; t4.y *= scale; t4.z *= scale; t4.w *= scale;
    *(float4*)&qs[r][c4] = t4;
  }
  if (tid < 64) { m_s[tid] = -3.0e38f; l_s[tid] = 0.f; }

  float o[8];
#pragma unroll
  for (int i = 0; i < 8; ++i) o[i] = 0.f;
  const int rB = (tid >> 5) * 8;
  const int cB = tid & 31;

  for (int m0 = 0; m0 < NTOK; m0 += 64) {
    __syncthreads();   // protect Ps/Vt/ks reuse (and first-iter qs/m_s init)
    const float* kptr = kb + ((size_t)bh * NTOK + m0) * 32;
    const float* vptr = vb + ((size_t)bh * NTOK + m0) * 32;
#pragma unroll
    for (int l = 0; l < 2; ++l) {
      int lin = tid + l * 256;
      int r = lin >> 3, c4 = (lin & 7) * 4;
      *(float4*)&ks[r][c4] = *(const float4*)&kptr[r * 32 + c4];
      float4 v4 = *(const float4*)&vptr[r * 32 + c4];
      Vt[c4 + 0][r] = v4.x; Vt[c4 + 1][r] = v4.y;
      Vt[c4 + 2][r] = v4.z; Vt[c4 + 3][r] = v4.w;
    }
    __syncthreads();

    // S[ty*4+i][tx+16j] = qs row . ks row
    float s[4][4];
#pragma unroll
    for (int i = 0; i < 4; ++i)
#pragma unroll
      for (int j = 0; j < 4; ++j) s[i][j] = 0.f;
#pragma unroll
    for (int k4 = 0; k4 < 8; ++k4) {
      float4 a4[4], b4[4];
#pragma unroll
      for (int i = 0; i < 4; ++i) a4[i] = *(float4*)&qs[ty * 4 + i][k4 * 4];
#pragma unroll
      for (int j = 0; j < 4; ++j) b4[j] = *(float4*)&ks[tx + 16 * j][k4 * 4];
#pragma unroll
      for (int i = 0; i < 4; ++i)
#pragma unroll
        for (int j = 0; j < 4; ++j)
          s[i][j] += a4[i].x * b4[j].x + a4[i].y * b4[j].y +
                     a4[i].z * b4[j].z + a4[i].w * b4[j].w;
    }

    // online softmax, row r = ty*4+i handled by its 16-lane tx group
#pragma unroll
    for (int i = 0; i < 4; ++i) {
      int r = ty * 4 + i;
      float mt = fmaxf(fmaxf(s[i][0], s[i][1]), fmaxf(s[i][2], s[i][3]));
#pragma unroll
      for (int msk = 1; msk < 16; msk <<= 1) mt = fmaxf(mt, __shfl_xor(mt, msk, 64));
      float mold = m_s[r];
      float mnew = fmaxf(mold, mt);
      float lsum = 0.f;
#pragma unroll
      for (int j = 0; j < 4; ++j) {
        float p = __expf(s[i][j] - mnew);
        s[i][j] = p; lsum += p;
      }
#pragma unroll
      for (int msk = 1; msk < 16; msk <<= 1) lsum += __shfl_xor(lsum, msk, 64);
      if (tx == 0) {
        float corr = __expf(mold - mnew);
        m_s[r] = mnew;
        sc_s[r] = corr;
        l_s[r] = l_s[r] * corr + lsum;
      }
#pragma unroll
      for (int j = 0; j < 4; ++j) Ps[r][tx + 16 * j] = s[i][j];
    }
    __syncthreads();

    // rescale O, accumulate P @ V
#pragma unroll
    for (int i = 0; i < 8; ++i) o[i] *= sc_s[rB + i];
#pragma unroll
    for (int mb = 0; mb < 16; ++mb) {
      float4 v4 = *(float4*)&Vt[cB][mb * 4];
#pragma unroll
      for (int i = 0; i < 8; ++i) {
        float4 p4 = *(float4*)&Ps[rB + i][mb * 4];
        o[i] += p4.x * v4.x + p4.y * v4.y + p4.z * v4.z + p4.w * v4.w;
      }
    }
  }

  float* optr = ob + ((size_t)bh * NTOK + r0) * 32;
#pragma unroll
  for (int i = 0; i < 8; ++i)
    optr[(rB + i) * 32 + cB] = o[i] / l_s[rB + i];
}

// ---------------------------------------------------------------------------
// K3: avg-pool per (b, channel): pool group g to SxS grid
// ---------------------------------------------------------------------------
template <int S>
__global__ void k_pool(const float* __restrict__ resb, float* __restrict__ pooled) {
  constexpr int G = (S == 1) ? 0 : (S == 2) ? 1 : (S == 3) ? 2 : 3;
  constexpr int WSZ = 48 / S;
  constexpr int NPX = WSZ * WSZ;
  int bi = blockIdx.x;            // b*64 + cc
  int b = bi >> 6, cc = bi & 63;
  int c = G * 64 + cc;
  int lane = threadIdx.x;
  const float* src = resb + ((size_t)b * 256 + c) * NTOK;
  const float inv = 1.f / NPX;
  for (int w = 0; w < S * S; ++w) {
    int wy = w / S, wx = w % S;
    float sum = 0.f;
    for (int idx = lane; idx < NPX; idx += 64) {
      int yy = wy * WSZ + idx / WSZ;
      int xx = wx * WSZ + idx % WSZ;
      sum += src[yy * 48 + xx];
    }
#pragma unroll
    for (int msk = 1; msk < 64; msk <<= 1) sum += __shfl_xor(sum, msk, 64);
    if (lane == 0) pooled[((size_t)b * 256 + c) * 36 + w] = sum * inv;
  }
}

// ---------------------------------------------------------------------------
// K4: dense conv 64->64 channels, constrained kernel (-1 center), k=3/5/7
// one block per (y row, b); 256 threads = 64 oc x 4 x-quarters of 12
// ---------------------------------------------------------------------------
template <int K>
__global__ __launch_bounds__(256) void k_conv(
    const float* __restrict__ resb, const float* __restrict__ kern,
    float* __restrict__ convb, int g) {
  constexpr int K2 = K * K, CTR = K2 / 2, P = K / 2, W = 48 + 2 * P;
  int y = blockIdx.x;
  int b = blockIdx.y;
  int tid = threadIdx.x;
  int oc = tid >> 2, xq = tid & 3;
  __shared__ float w_s[64][K2];
  __shared__ float in_s[K][W];
  float acc[12];
#pragma unroll
  for (int i = 0; i < 12; ++i) acc[i] = 0.f;
  const float* inb = resb + ((size_t)b * 256 + (g + 1) * 64) * NTOK;

  for (int ci = 0; ci < 64; ++ci) {
    for (int idx = tid; idx < 64 * K2; idx += 256) {
      int o = idx / K2, t = idx % K2;
      float wv = (t == CTR) ? -1.f
                            : kern[((size_t)o * 64 + ci) * (K2 - 1) + (t < CTR ? t : t - 1)];
      w_s[o][t] = wv;
    }
    for (int idx = tid; idx < K * W; idx += 256) {
      int ky = idx / W, xc = idx % W;
      int yy = y + ky - P, xx = xc - P;
      float vv = 0.f;
      if (yy >= 0 && yy < 48 && xx >= 0 && xx < 48)
        vv = inb[(size_t)ci * NTOK + yy * 48 + xx];
      in_s[ky][xc] = vv;
    }
    __syncthreads();
#pragma unroll
    for (int ky = 0; ky < K; ++ky) {
      float rv[12 + K - 1];
#pragma unroll
      for (int u = 0; u < 12 + K - 1; ++u) rv[u] = in_s[ky][xq * 12 + u];
#pragma unroll
      for (int kx = 0; kx < K; ++kx) {
        float wv = w_s[oc][ky * K + kx];
#pragma unroll
        for (int xx = 0; xx < 12; ++xx) acc[xx] += wv * rv[xx + kx];
      }
    }
    __syncthreads();
  }
  float* outp = convb + ((size_t)b * 192 + g * 64 + oc) * NTOK + y * 48 + xq * 12;
#pragma unroll
  for (int xx = 0; xx < 12; ++xx) outp[xx] = acc[xx];
}

// ---------------------------------------------------------------------------
// K5: combine  pre[b,n,c] = attn_out + q*conv_v + relu(bilinear_upsample(pool))
// ---------------------------------------------------------------------------
__global__ void k_combine(
    const float* __restrict__ qb, const float* __restrict__ accb,
    const float* __restrict__ resb, const float* __restrict__ convb,
    const float* __restrict__ pooled, float* __restrict__ pre) {
  int nt = blockIdx.x;           // 0..287
  int head = blockIdx.y;
  int b = blockIdx.z;
  int tid = threadIdx.x;
  int n = nt * 8 + (tid >> 5);
  int ch = tid & 31;
  int c = head * 32 + ch;
  int g = c >> 6;
  const int sArr[4] = {1, 2, 3, 6};
  int s = sArr[g];

  size_t qidx = (((size_t)b * 8 + head) * NTOK + n) * 32 + ch;
  float qv = qb[qidx];
  float av = accb[qidx];
  float cvv = (g == 0) ? resb[((size_t)b * 256 + c) * NTOK + n]
                       : convb[((size_t)b * 192 + (c - 64)) * NTOK + n];
  const float* pl = pooled + ((size_t)b * 256 + c) * 36;
  float lp;
  if (s == 1) {
    lp = pl[0];
  } else {
    int yy = n / 48, xx = n % 48;
    float fs = (float)(s - 1) / 47.0f;
    float ry = yy * fs, rx = xx * fs;
    int y0 = (int)ry, x0 = (int)rx;
    int y1 = min(y0 + 1, s - 1), x1 = min(x0 + 1, s - 1);
    float wy = ry - (float)y0, wx = rx - (float)x0;
    float v00 = pl[y0 * s + x0], v01 = pl[y0 * s + x1];
    float v10 = pl[y1 * s + x0], v11 = pl[y1 * s + x1];
    lp = v00 * (1 - wy) * (1 - wx) + v01 * (1 - wy) * wx +
         v10 * wy * (1 - wx) + v11 * wy * wx;
  }
  lp = fmaxf(lp, 0.f);
  pre[((size_t)b * NTOK + n) * 256 + c] = av + qv * cvv + lp;
}

// ---------------------------------------------------------------------------
// K6: final projection GEMM  out[9216,256] = pre @ wproj^T + bproj
// ---------------------------------------------------------------------------
__global__ __launch_bounds__(256) void k_gemm_proj(
    const float* __restrict__ pre, const float* __restrict__ wproj,
    const float* __restrict__ bproj, float* __restrict__ outp) {
  __shared__ __align__(16) float xs[128][20];
  __shared__ __align__(16) float ws[128][20];
  const int tid = threadIdx.x;
  const int ty = tid >> 4, tx = tid & 15;
  const int row0 = blockIdx.x * 128;
  const int col0 = blockIdx.y * 128;

  float acc[8][8];
#pragma unroll
  for (int i = 0; i < 8; ++i)
#pragma unroll
    for (int j = 0; j < 8; ++j) acc[i][j] = 0.f;

  for (int kc = 0; kc < 256; kc += 16) {
#pragma unroll
    for (int l = 0; l < 2; ++l) {
      int lin = tid + l * 256;
      int r = lin >> 2, kk = (lin & 3) * 4;
      *(float4*)&xs[r][kk] = *(const float4*)&pre[(size_t)(row0 + r) * 256 + kc + kk];
      *(float4*)&ws[r][kk] = *(const float4*)&wproj[(size_t)(col0 + r) * 256 + kc + kk];
    }
    __syncthreads();
#pragma unroll
    for (int k4 = 0; k4 < 4; ++k4) {
      float4 a4[8], b4[8];
#pragma unroll
      for (int i = 0; i < 8; ++i) a4[i] = *(float4*)&xs[ty + 16 * i][k4 * 4];
#pragma unroll
      for (int j = 0; j < 8; ++j) b4[j] = *(float4*)&ws[tx + 16 * j][k4 * 4];
#pragma unroll
      for (int i = 0; i < 8; ++i)
#pragma unroll
        for (int j = 0; j < 8; ++j)
          acc[i][j] += a4[i].x * b4[j].x + a4[i].y * b4[j].y +
                       a4[i].z * b4[j].z + a4[i].w * b4[j].w;
    }
    __syncthreads();
  }

#pragma unroll
  for (int i = 0; i < 8; ++i) {
    int row = row0 + ty + 16 * i;
#pragma unroll
    for (int j = 0; j < 8; ++j) {
      int col = col0 + tx + 16 * j;
      outp[(size_t)row * 256 + col] = acc[i][j] + bproj[col];
    }
  }
}

// ---------------------------------------------------------------------------
extern "C" void kernel_launch(void* const* d_in, const int* in_sizes, int n_in,
                              void* d_out, int out_size, void* d_ws, size_t ws_size,
                              hipStream_t stream) {
  const float* x     = (const float*)d_in[0];
  // d_in[1], d_in[2] are H, W (48, fixed)
  const float* wq    = (const float*)d_in[3];
  const float* wkv   = (const float*)d_in[4];
  const float* wres  = (const float*)d_in[5];
  const float* wproj = (const float*)d_in[6];
  const float* bproj = (const float*)d_in[7];
  const float* kern3 = (const float*)d_in[8];
  const float* kern5 = (const float*)d_in[9];
  const float* kern7 = (const float*)d_in[10];

  const size_t SZ = (size_t)4 * 8 * NTOK * 32;   // 2,359,296 floats per tensor
  float* wsf   = (float*)d_ws;
  float* qb    = wsf;
  float* kb    = qb + SZ;
  float* vb    = kb + SZ;
  float* resb  = vb + SZ;
  float* accb  = resb + SZ;
  // after attention, k/v buffers are dead: reuse
  float* preb   = kb;                    // (B,N,256)
  float* convb  = vb;                    // (B,192,N) = 1,769,472 floats
  float* pooled = vb + 1769472;          // (B,256,36) = 36,864 floats
  float* outp  = (float*)d_out;

  k_gemm_qkvres<<<dim3(72, 8), 256, 0, stream>>>(x, wq, wkv, wres, qb, kb, vb, resb);
  k_attn<<<dim3(36, 32), 256, 0, stream>>>(qb, kb, vb, accb);
  k_pool<1><<<dim3(256), 64, 0, stream>>>(resb, pooled);
  k_pool<2><<<dim3(256), 64, 0, stream>>>(resb, pooled);
  k_pool<3><<<dim3(256), 64, 0, stream>>>(resb, pooled);
  k_pool<6><<<dim3(256), 64, 0, stream>>>(resb, pooled);
  k_conv<3><<<dim3(48, 4), 256, 0, stream>>>(resb, kern3, convb, 0);
  k_conv<5><<<dim3(48, 4), 256, 0, stream>>>(resb, kern5, convb, 1);
  k_conv<7><<<dim3(48, 4), 256, 0, stream>>>(resb, kern7, convb, 2);
  k_combine<<<dim3(288, 8, 4), 256, 0, stream>>>(qb, accb, resb, convb, pooled, preb);
  k_gemm_proj<<<dim3(72, 2), 256, 0, stream>>>(preb, wproj, bproj, outp);
}

// Round 2
// 1100.339 us; speedup vs baseline: 1.7628x; 1.7628x over previous
//
#include <hip/hip_runtime.h>
#include <math.h>

#define NTOK 2304   // N = 48*48
#define DIMC 256

typedef __attribute__((ext_vector_type(8))) short short8;
typedef __attribute__((ext_vector_type(4))) float f32x4;

__device__ __forceinline__ unsigned short f2bf(float f) {
  unsigned u = __float_as_uint(f);
  u += 0x7fffu + ((u >> 16) & 1u);
  return (unsigned short)(u >> 16);
}
__device__ __forceinline__ float bf2f(unsigned short h) {
  return __uint_as_float(((unsigned)h) << 16);
}

// ---------------------------------------------------------------------------
// K1: fused GEMM  Y[9216,1024] = X[9216,256] @ [wq;wkv;wres]^T
// epilogue: q -> fp32 [bh][n][32]; k -> bf16 hi/lo [bh][n][32];
//           v -> bf16 hi transposed [bh][32][n]; res -> relu fp32 [b][c][n]
// ---------------------------------------------------------------------------
__global__ __launch_bounds__(256) void k_gemm_qkvres(
    const float* __restrict__ x, const float* __restrict__ wq,
    const float* __restrict__ wkv, const float* __restrict__ wres,
    float* __restrict__ qb, unsigned short* __restrict__ khi,
    unsigned short* __restrict__ klo, unsigned short* __restrict__ vT,
    float* __restrict__ resb) {
  __shared__ __align__(16) float xs[128][20];
  __shared__ __align__(16) float ws[128][20];
  const int tid = threadIdx.x;
  const int ty = tid >> 4, tx = tid & 15;
  const int row0 = blockIdx.x * 128;
  const int col0 = blockIdx.y * 128;
  const float* wbase; int wr0;
  if (col0 < 256)      { wbase = wq;   wr0 = col0; }
  else if (col0 < 768) { wbase = wkv;  wr0 = col0 - 256; }
  else                 { wbase = wres; wr0 = col0 - 768; }

  float acc[8][8];
#pragma unroll
  for (int i = 0; i < 8; ++i)
#pragma unroll
    for (int j = 0; j < 8; ++j) acc[i][j] = 0.f;

  for (int kc = 0; kc < 256; kc += 16) {
#pragma unroll
    for (int l = 0; l < 2; ++l) {
      int lin = tid + l * 256;
      int r = lin >> 2;
      int kk = (lin & 3) * 4;
      *(float4*)&xs[r][kk] = *(const float4*)&x[(size_t)(row0 + r) * 256 + kc + kk];
      *(float4*)&ws[r][kk] = *(const float4*)&wbase[(size_t)(wr0 + r) * 256 + kc + kk];
    }
    __syncthreads();
#pragma unroll
    for (int k4 = 0; k4 < 4; ++k4) {
      float4 a4[8], b4[8];
#pragma unroll
      for (int i = 0; i < 8; ++i) a4[i] = *(float4*)&xs[ty + 16 * i][k4 * 4];
#pragma unroll
      for (int j = 0; j < 8; ++j) b4[j] = *(float4*)&ws[tx + 16 * j][k4 * 4];
#pragma unroll
      for (int i = 0; i < 8; ++i)
#pragma unroll
        for (int j = 0; j < 8; ++j)
          acc[i][j] += a4[i].x * b4[j].x + a4[i].y * b4[j].y +
                       a4[i].z * b4[j].z + a4[i].w * b4[j].w;
    }
    __syncthreads();
  }

#pragma unroll
  for (int i = 0; i < 8; ++i) {
    int row = row0 + ty + 16 * i;
    int b = row / NTOK;
    int n = row % NTOK;
#pragma unroll
    for (int j = 0; j < 8; ++j) {
      int col = col0 + tx + 16 * j;
      float vv = acc[i][j];
      if (col < 256) {
        int head = col >> 5, ch = col & 31;
        qb[(((size_t)b * 8 + head) * NTOK + n) * 32 + ch] = vv;
      } else if (col < 512) {
        int o = col - 256; int head = o >> 5, ch = o & 31;
        size_t idx = (((size_t)b * 8 + head) * NTOK + n) * 32 + ch;
        unsigned short h = f2bf(vv);
        khi[idx] = h;
        klo[idx] = f2bf(vv - bf2f(h));
      } else if (col < 768) {
        int o = col - 512; int head = o >> 5, ch = o & 31;
        vT[(((size_t)b * 8 + head) * 32 + ch) * NTOK + n] = f2bf(vv);
      } else {
        int c = col - 768;
        resb[((size_t)b * 256 + c) * NTOK + n] = fmaxf(vv, 0.f);
      }
    }
  }
}

// ---------------------------------------------------------------------------
// K2: MFMA flash attention. Block = (b,h) x 128 q-rows, 8 waves x 16 q-rows.
// KV tiles of 64. QK^T: 3-term split-bf16 (fp32-grade S). PV: single bf16.
// ---------------------------------------------------------------------------
__global__ __launch_bounds__(512, 4) void k_attn_mfma(
    const float* __restrict__ qb, const unsigned short* __restrict__ khi,
    const unsigned short* __restrict__ klo, const unsigned short* __restrict__ vT,
    float* __restrict__ accb) {
  const int bh = blockIdx.y;
  const int r0 = blockIdx.x * 128;
  const int tid = threadIdx.x;
  const int w = tid >> 6;
  const int lane = tid & 63;
  const int lg = lane >> 4;      // 0..3
  const int lc = lane & 15;      // 0..15

  // padded, 16B-aligned strides chosen for conflict-free ds_read_b128
  __shared__ __align__(16) unsigned short ks_hi[64][40];
  __shared__ __align__(16) unsigned short ks_lo[64][40];
  __shared__ __align__(16) unsigned short vs[32][72];
  __shared__ __align__(16) unsigned short ps[8][16][72];

  const float scale = 0.17677669529663688f;   // 32^-0.5

  // Q fragment (A-layout: m=lc, k=lg*8+i), scaled + split hi/lo. Lives in regs.
  const float* qp = qb + (((size_t)bh * NTOK + r0 + w * 16 + lc) * 32 + lg * 8);
  float qf[8];
  *(float4*)&qf[0] = *(const float4*)qp;
  *(float4*)&qf[4] = *(const float4*)(qp + 4);
  short8 qh, ql;
#pragma unroll
  for (int i = 0; i < 8; ++i) {
    float v = qf[i] * scale;
    unsigned short h = f2bf(v);
    qh[i] = (short)h;
    ql[i] = (short)f2bf(v - bf2f(h));
  }

  float m_r[4], l_r[4];
#pragma unroll
  for (int j = 0; j < 4; ++j) { m_r[j] = -3.0e38f; l_r[j] = 0.f; }
  f32x4 o0 = {0.f, 0.f, 0.f, 0.f};
  f32x4 o1 = {0.f, 0.f, 0.f, 0.f};

  const int srow = tid >> 3, sq8 = tid & 7;       // khi/klo staging: 64 rows x 8
  const int vrow = tid >> 4, vp = tid & 15;       // vT staging: 32 rows x 16

  for (int kt = 0; kt < 36; ++kt) {
    const int kv0 = kt * 64;
    __syncthreads();
    // ---- stage K (hi,lo) and V^T tiles into LDS (reg-staged, padded dest)
    *(uint2*)&ks_hi[srow][sq8 * 4] =
        *(const uint2*)(khi + ((size_t)bh * NTOK + kv0 + srow) * 32 + sq8 * 4);
    *(uint2*)&ks_lo[srow][sq8 * 4] =
        *(const uint2*)(klo + ((size_t)bh * NTOK + kv0 + srow) * 32 + sq8 * 4);
    *(uint2*)&vs[vrow][vp * 4] =
        *(const uint2*)(vT + ((size_t)bh * 32 + vrow) * NTOK + kv0 + vp * 4);
    __syncthreads();

    // ---- S = Q K^T  (4 n-tiles of 16 kv, 3 split MFMAs each)
    f32x4 s[4];
#pragma unroll
    for (int nt = 0; nt < 4; ++nt) {
      short8 kh = *(short8*)&ks_hi[lc + 16 * nt][lg * 8];
      short8 kl = *(short8*)&ks_lo[lc + 16 * nt][lg * 8];
      f32x4 a = {0.f, 0.f, 0.f, 0.f};
      a = __builtin_amdgcn_mfma_f32_16x16x32_bf16(qh, kh, a, 0, 0, 0);
      a = __builtin_amdgcn_mfma_f32_16x16x32_bf16(qh, kl, a, 0, 0, 0);
      a = __builtin_amdgcn_mfma_f32_16x16x32_bf16(ql, kh, a, 0, 0, 0);
      s[nt] = a;
    }

    // ---- online softmax (row j of this lane group = q-row lg*4+j)
#pragma unroll
    for (int j = 0; j < 4; ++j) {
      float mt = fmaxf(fmaxf(s[0][j], s[1][j]), fmaxf(s[2][j], s[3][j]));
#pragma unroll
      for (int msk = 1; msk < 16; msk <<= 1) mt = fmaxf(mt, __shfl_xor(mt, msk, 64));
      float mn = fmaxf(m_r[j], mt);
      float corr = __expf(m_r[j] - mn);
      m_r[j] = mn;
      float ls = 0.f;
#pragma unroll
      for (int nt = 0; nt < 4; ++nt) {
        float p = __expf(s[nt][j] - mn);
        s[nt][j] = p;
        ls += p;
      }
#pragma unroll
      for (int msk = 1; msk < 16; msk <<= 1) ls += __shfl_xor(ls, msk, 64);
      l_r[j] = l_r[j] * corr + ls;
      o0[j] *= corr;
      o1[j] *= corr;
    }

    // ---- P -> bf16 -> per-wave LDS (D-layout write, A-layout read)
#pragma unroll
    for (int nt = 0; nt < 4; ++nt)
#pragma unroll
      for (int j = 0; j < 4; ++j)
        ps[w][lg * 4 + j][nt * 16 + lc] = f2bf(s[nt][j]);

    __builtin_amdgcn_sched_barrier(0);
    asm volatile("s_waitcnt lgkmcnt(0)" ::: "memory");
    __builtin_amdgcn_sched_barrier(0);

    // ---- O += P V  (2 kv-chunks of 32, 2 channel n-tiles)
#pragma unroll
    for (int h2 = 0; h2 < 2; ++h2) {
      short8 pa = *(short8*)&ps[w][lc][h2 * 32 + lg * 8];
      short8 v0 = *(short8*)&vs[lc][h2 * 32 + lg * 8];
      short8 v1 = *(short8*)&vs[lc + 16][h2 * 32 + lg * 8];
      o0 = __builtin_amdgcn_mfma_f32_16x16x32_bf16(pa, v0, o0, 0, 0, 0);
      o1 = __builtin_amdgcn_mfma_f32_16x16x32_bf16(pa, v1, o1, 0, 0, 0);
    }
  }

  float* op = accb + ((size_t)bh * NTOK + r0 + w * 16) * 32;
#pragma unroll
  for (int j = 0; j < 4; ++j) {
    float inv = 1.f / l_r[j];
    int r = lg * 4 + j;
    op[r * 32 + lc] = o0[j] * inv;
    op[r * 32 + lc + 16] = o1[j] * inv;
  }
}

// ---------------------------------------------------------------------------
// K3: avg-pool per (b, channel): pool group g to SxS grid
// ---------------------------------------------------------------------------
template <int S>
__global__ void k_pool(const float* __restrict__ resb, float* __restrict__ pooled) {
  constexpr int G = (S == 1) ? 0 : (S == 2) ? 1 : (S == 3) ? 2 : 3;
  constexpr int WSZ = 48 / S;
  constexpr int NPX = WSZ * WSZ;
  int bi = blockIdx.x;
  int b = bi >> 6, cc = bi & 63;
  int c = G * 64 + cc;
  int lane = threadIdx.x;
  const float* src = resb + ((size_t)b * 256 + c) * NTOK;
  const float inv = 1.f / NPX;
  for (int w = 0; w < S * S; ++w) {
    int wy = w / S, wx = w % S;
    float sum = 0.f;
    for (int idx = lane; idx < NPX; idx += 64) {
      int yy = wy * WSZ + idx / WSZ;
      int xx = wx * WSZ + idx % WSZ;
      sum += src[yy * 48 + xx];
    }
#pragma unroll
    for (int msk = 1; msk < 64; msk <<= 1) sum += __shfl_xor(sum, msk, 64);
    if (lane == 0) pooled[((size_t)b * 256 + c) * 36 + w] = sum * inv;
  }
}

// ---------------------------------------------------------------------------
// K4: dense conv 64->64 channels, constrained kernel (-1 center), k=3/5/7
// ---------------------------------------------------------------------------
template <int K>
__global__ __launch_bounds__(256) void k_conv(
    const float* __restrict__ resb, const float* __restrict__ kern,
    float* __restrict__ convb, int g) {
  constexpr int K2 = K * K, CTR = K2 / 2, P = K / 2, W = 48 + 2 * P;
  int y = blockIdx.x;
  int b = blockIdx.y;
  int tid = threadIdx.x;
  int oc = tid >> 2, xq = tid & 3;
  __shared__ float w_s[64][K2];
  __shared__ float in_s[K][W];
  float acc[12];
#pragma unroll
  for (int i = 0; i < 12; ++i) acc[i] = 0.f;
  const float* inb = resb + ((size_t)b * 256 + (g + 1) * 64) * NTOK;

  for (int ci = 0; ci < 64; ++ci) {
    for (int idx = tid; idx < 64 * K2; idx += 256) {
      int o = idx / K2, t = idx % K2;
      float wv = (t == CTR) ? -1.f
                            : kern[((size_t)o * 64 + ci) * (K2 - 1) + (t < CTR ? t : t - 1)];
      w_s[o][t] = wv;
    }
    for (int idx = tid; idx < K * W; idx += 256) {
      int ky = idx / W, xc = idx % W;
      int yy = y + ky - P, xx = xc - P;
      float vv = 0.f;
      if (yy >= 0 && yy < 48 && xx >= 0 && xx < 48)
        vv = inb[(size_t)ci * NTOK + yy * 48 + xx];
      in_s[ky][xc] = vv;
    }
    __syncthreads();
#pragma unroll
    for (int ky = 0; ky < K; ++ky) {
      float rv[12 + K - 1];
#pragma unroll
      for (int u = 0; u < 12 + K - 1; ++u) rv[u] = in_s[ky][xq * 12 + u];
#pragma unroll
      for (int kx = 0; kx < K; ++kx) {
        float wv = w_s[oc][ky * K + kx];
#pragma unroll
        for (int xx = 0; xx < 12; ++xx) acc[xx] += wv * rv[xx + kx];
      }
    }
    __syncthreads();
  }
  float* outp = convb + ((size_t)b * 192 + g * 64 + oc) * NTOK + y * 48 + xq * 12;
#pragma unroll
  for (int xx = 0; xx < 12; ++xx) outp[xx] = acc[xx];
}

// ---------------------------------------------------------------------------
// K5: combine  pre[b,n,c] = attn_out + q*conv_v + relu(bilinear_upsample(pool))
// ---------------------------------------------------------------------------
__global__ void k_combine(
    const float* __restrict__ qb, const float* __restrict__ accb,
    const float* __restrict__ resb, const float* __restrict__ convb,
    const float* __restrict__ pooled, float* __restrict__ pre) {
  int nt = blockIdx.x;
  int head = blockIdx.y;
  int b = blockIdx.z;
  int tid = threadIdx.x;
  int n = nt * 8 + (tid >> 5);
  int ch = tid & 31;
  int c = head * 32 + ch;
  int g = c >> 6;
  const int sArr[4] = {1, 2, 3, 6};
  int s = sArr[g];

  size_t qidx = (((size_t)b * 8 + head) * NTOK + n) * 32 + ch;
  float qv = qb[qidx];
  float av = accb[qidx];
  float cvv = (g == 0) ? resb[((size_t)b * 256 + c) * NTOK + n]
                       : convb[((size_t)b * 192 + (c - 64)) * NTOK + n];
  const float* pl = pooled + ((size_t)b * 256 + c) * 36;
  float lp;
  if (s == 1) {
    lp = pl[0];
  } else {
    int yy = n / 48, xx = n % 48;
    float fs = (float)(s - 1) / 47.0f;
    float ry = yy * fs, rx = xx * fs;
    int y0 = (int)ry, x0 = (int)rx;
    int y1 = min(y0 + 1, s - 1), x1 = min(x0 + 1, s - 1);
    float wy = ry - (float)y0, wx = rx - (float)x0;
    float v00 = pl[y0 * s + x0], v01 = pl[y0 * s + x1];
    float v10 = pl[y1 * s + x0], v11 = pl[y1 * s + x1];
    lp = v00 * (1 - wy) * (1 - wx) + v01 * (1 - wy) * wx +
         v10 * wy * (1 - wx) + v11 * wy * wx;
  }
  lp = fmaxf(lp, 0.f);
  pre[((size_t)b * NTOK + n) * 256 + c] = av + qv * cvv + lp;
}

// ---------------------------------------------------------------------------
// K6: final projection GEMM  out[9216,256] = pre @ wproj^T + bproj
// ---------------------------------------------------------------------------
__global__ __launch_bounds__(256) void k_gemm_proj(
    const float* __restrict__ pre, const float* __restrict__ wproj,
    const float* __restrict__ bproj, float* __restrict__ outp) {
  __shared__ __align__(16) float xs[128][20];
  __shared__ __align__(16) float ws[128][20];
  const int tid = threadIdx.x;
  const int ty = tid >> 4, tx = tid & 15;
  const int row0 = blockIdx.x * 128;
  const int col0 = blockIdx.y * 128;

  float acc[8][8];
#pragma unroll
  for (int i = 0; i < 8; ++i)
#pragma unroll
    for (int j = 0; j < 8; ++j) acc[i][j] = 0.f;

  for (int kc = 0; kc < 256; kc += 16) {
#pragma unroll
    for (int l = 0; l < 2; ++l) {
      int lin = tid + l * 256;
      int r = lin >> 2, kk = (lin & 3) * 4;
      *(float4*)&xs[r][kk] = *(const float4*)&pre[(size_t)(row0 + r) * 256 + kc + kk];
      *(float4*)&ws[r][kk] = *(const float4*)&wproj[(size_t)(col0 + r) * 256 + kc + kk];
    }
    __syncthreads();
#pragma unroll
    for (int k4 = 0; k4 < 4; ++k4) {
      float4 a4[8], b4[8];
#pragma unroll
      for (int i = 0; i < 8; ++i) a4[i] = *(float4*)&xs[ty + 16 * i][k4 * 4];
#pragma unroll
      for (int j = 0; j < 8; ++j) b4[j] = *(float4*)&ws[tx + 16 * j][k4 * 4];
#pragma unroll
      for (int i = 0; i < 8; ++i)
#pragma unroll
        for (int j = 0; j < 8; ++j)
          acc[i][j] += a4[i].x * b4[j].x + a4[i].y * b4[j].y +
                       a4[i].z * b4[j].z + a4[i].w * b4[j].w;
    }
    __syncthreads();
  }

#pragma unroll
  for (int i = 0; i < 8; ++i) {
    int row = row0 + ty + 16 * i;
#pragma unroll
    for (int j = 0; j < 8; ++j) {
      int col = col0 + tx + 16 * j;
      outp[(size_t)row * 256 + col] = acc[i][j] + bproj[col];
    }
  }
}

// ---------------------------------------------------------------------------
extern "C" void kernel_launch(void* const* d_in, const int* in_sizes, int n_in,
                              void* d_out, int out_size, void* d_ws, size_t ws_size,
                              hipStream_t stream) {
  const float* x     = (const float*)d_in[0];
  const float* wq    = (const float*)d_in[3];
  const float* wkv   = (const float*)d_in[4];
  const float* wres  = (const float*)d_in[5];
  const float* wproj = (const float*)d_in[6];
  const float* bproj = (const float*)d_in[7];
  const float* kern3 = (const float*)d_in[8];
  const float* kern5 = (const float*)d_in[9];
  const float* kern7 = (const float*)d_in[10];

  const size_t SZ = (size_t)4 * 8 * NTOK * 32;   // 2,359,296
  float* wsf  = (float*)d_ws;
  float* qb   = wsf;                              // [0, SZ)
  float* resb = wsf + SZ;                         // [SZ, 2SZ)
  float* accb = wsf + 2 * SZ;                     // [2SZ, 3SZ)
  unsigned short* khi = (unsigned short*)(wsf + 3 * SZ);           // SZ ushorts
  unsigned short* klo = (unsigned short*)(wsf + 3 * SZ + SZ / 2);  // SZ ushorts
  unsigned short* vT  = (unsigned short*)(wsf + 4 * SZ);           // SZ ushorts
  float* preb = wsf + 4 * SZ + SZ / 2;            // [4.5SZ, 5.5SZ)
  // dead after attention -> reuse:
  float* convb  = wsf + 3 * SZ;                   // 1,769,472 floats (in khi/klo)
  float* pooled = wsf + 4 * SZ;                   // 36,864 floats   (in vT)
  float* outp = (float*)d_out;

  k_gemm_qkvres<<<dim3(72, 8), 256, 0, stream>>>(x, wq, wkv, wres, qb, khi, klo, vT, resb);
  k_attn_mfma<<<dim3(18, 32), 512, 0, stream>>>(qb, khi, klo, vT, accb);
  k_pool<1><<<dim3(256), 64, 0, stream>>>(resb, pooled);
  k_pool<2><<<dim3(256), 64, 0, stream>>>(resb, pooled);
  k_pool<3><<<dim3(256), 64, 0, stream>>>(resb, pooled);
  k_pool<6><<<dim3(256), 64, 0, stream>>>(resb, pooled);
  k_conv<3><<<dim3(48, 4), 256, 0, stream>>>(resb, kern3, convb, 0);
  k_conv<5><<<dim3(48, 4), 256, 0, stream>>>(resb, kern5, convb, 1);
  k_conv<7><<<dim3(48, 4), 256, 0, stream>>>(resb, kern7, convb, 2);
  k_combine<<<dim3(288, 8, 4), 256, 0, stream>>>(qb, accb, resb, convb, pooled, preb);
  k_gemm_proj<<<dim3(72, 2), 256, 0, stream>>>(preb, wproj, bproj, outp);
}

// Round 3
// 497.274 us; speedup vs baseline: 3.9006x; 2.2127x over previous
//
#include <hip/hip_runtime.h>
#include <math.h>

#define NTOK 2304   // N = 48*48
#define DIMC 256

typedef __attribute__((ext_vector_type(8))) short short8;
typedef __attribute__((ext_vector_type(4))) float f32x4;

__device__ __forceinline__ unsigned short f2bf(float f) {
  unsigned u = __float_as_uint(f);
  u += 0x7fffu + ((u >> 16) & 1u);
  return (unsigned short)(u >> 16);
}
__device__ __forceinline__ float bf2f(unsigned short h) {
  return __uint_as_float(((unsigned)h) << 16);
}

// ---------------------------------------------------------------------------
// K1: fused GEMM  Y[9216,1024] = X[9216,256] @ [wq;wkv;wres]^T
// epilogue: q fp32 [bh][n][32]; k bf16 hi/lo [bh][n][32]; v bf16 T [bh][32][n];
//           res relu fp32 [b][c][n]  +  bf16 channel-contig resT[b][g][px][64]
// ---------------------------------------------------------------------------
__global__ __launch_bounds__(256) void k_gemm_qkvres(
    const float* __restrict__ x, const float* __restrict__ wq,
    const float* __restrict__ wkv, const float* __restrict__ wres,
    float* __restrict__ qb, unsigned short* __restrict__ khi,
    unsigned short* __restrict__ klo, unsigned short* __restrict__ vT,
    float* __restrict__ resb, unsigned short* __restrict__ resT) {
  __shared__ __align__(16) float xs[128][20];
  __shared__ __align__(16) float ws[128][20];
  const int tid = threadIdx.x;
  const int ty = tid >> 4, tx = tid & 15;
  const int row0 = blockIdx.x * 128;
  const int col0 = blockIdx.y * 128;
  const float* wbase; int wr0;
  if (col0 < 256)      { wbase = wq;   wr0 = col0; }
  else if (col0 < 768) { wbase = wkv;  wr0 = col0 - 256; }
  else                 { wbase = wres; wr0 = col0 - 768; }

  float acc[8][8];
#pragma unroll
  for (int i = 0; i < 8; ++i)
#pragma unroll
    for (int j = 0; j < 8; ++j) acc[i][j] = 0.f;

  for (int kc = 0; kc < 256; kc += 16) {
#pragma unroll
    for (int l = 0; l < 2; ++l) {
      int lin = tid + l * 256;
      int r = lin >> 2;
      int kk = (lin & 3) * 4;
      *(float4*)&xs[r][kk] = *(const float4*)&x[(size_t)(row0 + r) * 256 + kc + kk];
      *(float4*)&ws[r][kk] = *(const float4*)&wbase[(size_t)(wr0 + r) * 256 + kc + kk];
    }
    __syncthreads();
#pragma unroll
    for (int k4 = 0; k4 < 4; ++k4) {
      float4 a4[8], b4[8];
#pragma unroll
      for (int i = 0; i < 8; ++i) a4[i] = *(float4*)&xs[ty + 16 * i][k4 * 4];
#pragma unroll
      for (int j = 0; j < 8; ++j) b4[j] = *(float4*)&ws[tx + 16 * j][k4 * 4];
#pragma unroll
      for (int i = 0; i < 8; ++i)
#pragma unroll
        for (int j = 0; j < 8; ++j)
          acc[i][j] += a4[i].x * b4[j].x + a4[i].y * b4[j].y +
                       a4[i].z * b4[j].z + a4[i].w * b4[j].w;
    }
    __syncthreads();
  }

#pragma unroll
  for (int i = 0; i < 8; ++i) {
    int row = row0 + ty + 16 * i;
    int b = row / NTOK;
    int n = row % NTOK;
#pragma unroll
    for (int j = 0; j < 8; ++j) {
      int col = col0 + tx + 16 * j;
      float vv = acc[i][j];
      if (col < 256) {
        int head = col >> 5, ch = col & 31;
        qb[(((size_t)b * 8 + head) * NTOK + n) * 32 + ch] = vv;
      } else if (col < 512) {
        int o = col - 256; int head = o >> 5, ch = o & 31;
        size_t idx = (((size_t)b * 8 + head) * NTOK + n) * 32 + ch;
        unsigned short h = f2bf(vv);
        khi[idx] = h;
        klo[idx] = f2bf(vv - bf2f(h));
      } else if (col < 768) {
        int o = col - 512; int head = o >> 5, ch = o & 31;
        vT[(((size_t)b * 8 + head) * 32 + ch) * NTOK + n] = f2bf(vv);
      } else {
        int c = col - 768;
        float rv = fmaxf(vv, 0.f);
        resb[((size_t)b * 256 + c) * NTOK + n] = rv;
        if (c >= 64) {
          int g = (c >> 6) - 1, ic = c & 63;
          resT[(((size_t)b * 3 + g) * NTOK + n) * 64 + ic] = f2bf(rv);
        }
      }
    }
  }
}

// ---------------------------------------------------------------------------
// K1b: constrained conv weights -> bf16  wT[(tapbase+t)*4096 + oc*64 + ic]
// tap bases: k3 -> 0 (9 taps), k5 -> 9 (25), k7 -> 34 (49); total 83*4096
// ---------------------------------------------------------------------------
__global__ void k_wprep(const float* __restrict__ k3, const float* __restrict__ k5,
                        const float* __restrict__ k7, unsigned short* __restrict__ wT) {
  int idx = blockIdx.x * 512 + threadIdx.x;
  if (idx >= 83 * 4096) return;
  const float* src; int K, tloc;
  if (idx < 9 * 4096)       { K = 3; src = k3; tloc = idx >> 12; }
  else if (idx < 34 * 4096) { K = 5; src = k5; tloc = (idx - 9 * 4096) >> 12; }
  else                      { K = 7; src = k7; tloc = (idx - 34 * 4096) >> 12; }
  int r = idx & 4095, oc = r >> 6, ic = r & 63;
  int K2 = K * K, ctr = K2 / 2;
  float v = (tloc == ctr) ? -1.f
          : src[((size_t)oc * 64 + ic) * (K2 - 1) + (tloc < ctr ? tloc : tloc - 1)];
  wT[idx] = f2bf(v);
}

// ---------------------------------------------------------------------------
// K2: MFMA flash attention (unchanged from round 1)
// ---------------------------------------------------------------------------
__global__ __launch_bounds__(512, 4) void k_attn_mfma(
    const float* __restrict__ qb, const unsigned short* __restrict__ khi,
    const unsigned short* __restrict__ klo, const unsigned short* __restrict__ vT,
    float* __restrict__ accb) {
  const int bh = blockIdx.y;
  const int r0 = blockIdx.x * 128;
  const int tid = threadIdx.x;
  const int w = tid >> 6;
  const int lane = tid & 63;
  const int lg = lane >> 4;
  const int lc = lane & 15;

  __shared__ __align__(16) unsigned short ks_hi[64][40];
  __shared__ __align__(16) unsigned short ks_lo[64][40];
  __shared__ __align__(16) unsigned short vs[32][72];
  __shared__ __align__(16) unsigned short ps[8][16][72];

  const float scale = 0.17677669529663688f;

  const float* qp = qb + (((size_t)bh * NTOK + r0 + w * 16 + lc) * 32 + lg * 8);
  float qf[8];
  *(float4*)&qf[0] = *(const float4*)qp;
  *(float4*)&qf[4] = *(const float4*)(qp + 4);
  short8 qh, ql;
#pragma unroll
  for (int i = 0; i < 8; ++i) {
    float v = qf[i] * scale;
    unsigned short h = f2bf(v);
    qh[i] = (short)h;
    ql[i] = (short)f2bf(v - bf2f(h));
  }

  float m_r[4], l_r[4];
#pragma unroll
  for (int j = 0; j < 4; ++j) { m_r[j] = -3.0e38f; l_r[j] = 0.f; }
  f32x4 o0 = {0.f, 0.f, 0.f, 0.f};
  f32x4 o1 = {0.f, 0.f, 0.f, 0.f};

  const int srow = tid >> 3, sq8 = tid & 7;
  const int vrow = tid >> 4, vp = tid & 15;

  for (int kt = 0; kt < 36; ++kt) {
    const int kv0 = kt * 64;
    __syncthreads();
    *(uint2*)&ks_hi[srow][sq8 * 4] =
        *(const uint2*)(khi + ((size_t)bh * NTOK + kv0 + srow) * 32 + sq8 * 4);
    *(uint2*)&ks_lo[srow][sq8 * 4] =
        *(const uint2*)(klo + ((size_t)bh * NTOK + kv0 + srow) * 32 + sq8 * 4);
    *(uint2*)&vs[vrow][vp * 4] =
        *(const uint2*)(vT + ((size_t)bh * 32 + vrow) * NTOK + kv0 + vp * 4);
    __syncthreads();

    f32x4 s[4];
#pragma unroll
    for (int nt = 0; nt < 4; ++nt) {
      short8 kh = *(short8*)&ks_hi[lc + 16 * nt][lg * 8];
      short8 kl = *(short8*)&ks_lo[lc + 16 * nt][lg * 8];
      f32x4 a = {0.f, 0.f, 0.f, 0.f};
      a = __builtin_amdgcn_mfma_f32_16x16x32_bf16(qh, kh, a, 0, 0, 0);
      a = __builtin_amdgcn_mfma_f32_16x16x32_bf16(qh, kl, a, 0, 0, 0);
      a = __builtin_amdgcn_mfma_f32_16x16x32_bf16(ql, kh, a, 0, 0, 0);
      s[nt] = a;
    }

#pragma unroll
    for (int j = 0; j < 4; ++j) {
      float mt = fmaxf(fmaxf(s[0][j], s[1][j]), fmaxf(s[2][j], s[3][j]));
#pragma unroll
      for (int msk = 1; msk < 16; msk <<= 1) mt = fmaxf(mt, __shfl_xor(mt, msk, 64));
      float mn = fmaxf(m_r[j], mt);
      float corr = __expf(m_r[j] - mn);
      m_r[j] = mn;
      float ls = 0.f;
#pragma unroll
      for (int nt = 0; nt < 4; ++nt) {
        float p = __expf(s[nt][j] - mn);
        s[nt][j] = p;
        ls += p;
      }
#pragma unroll
      for (int msk = 1; msk < 16; msk <<= 1) ls += __shfl_xor(ls, msk, 64);
      l_r[j] = l_r[j] * corr + ls;
      o0[j] *= corr;
      o1[j] *= corr;
    }

#pragma unroll
    for (int nt = 0; nt < 4; ++nt)
#pragma unroll
      for (int j = 0; j < 4; ++j)
        ps[w][lg * 4 + j][nt * 16 + lc] = f2bf(s[nt][j]);

    __builtin_amdgcn_sched_barrier(0);
    asm volatile("s_waitcnt lgkmcnt(0)" ::: "memory");
    __builtin_amdgcn_sched_barrier(0);

#pragma unroll
    for (int h2 = 0; h2 < 2; ++h2) {
      short8 pa = *(short8*)&ps[w][lc][h2 * 32 + lg * 8];
      short8 v0 = *(short8*)&vs[lc][h2 * 32 + lg * 8];
      short8 v1 = *(short8*)&vs[lc + 16][h2 * 32 + lg * 8];
      o0 = __builtin_amdgcn_mfma_f32_16x16x32_bf16(pa, v0, o0, 0, 0, 0);
      o1 = __builtin_amdgcn_mfma_f32_16x16x32_bf16(pa, v1, o1, 0, 0, 0);
    }
  }

  float* op = accb + ((size_t)bh * NTOK + r0 + w * 16) * 32;
#pragma unroll
  for (int j = 0; j < 4; ++j) {
    float inv = 1.f / l_r[j];
    int r = lg * 4 + j;
    op[r * 32 + lc] = o0[j] * inv;
    op[r * 32 + lc + 16] = o1[j] * inv;
  }
}

// ---------------------------------------------------------------------------
// K3: avg-pool per (b, channel)
// ---------------------------------------------------------------------------
template <int S>
__global__ void k_pool(const float* __restrict__ resb, float* __restrict__ pooled) {
  constexpr int G = (S == 1) ? 0 : (S == 2) ? 1 : (S == 3) ? 2 : 3;
  constexpr int WSZ = 48 / S;
  constexpr int NPX = WSZ * WSZ;
  int bi = blockIdx.x;
  int b = bi >> 6, cc = bi & 63;
  int c = G * 64 + cc;
  int lane = threadIdx.x;
  const float* src = resb + ((size_t)b * 256 + c) * NTOK;
  const float inv = 1.f / NPX;
  for (int w = 0; w < S * S; ++w) {
    int wy = w / S, wx = w % S;
    float sum = 0.f;
    for (int idx = lane; idx < NPX; idx += 64) {
      int yy = wy * WSZ + idx / WSZ;
      int xx = wx * WSZ + idx % WSZ;
      sum += src[yy * 48 + xx];
    }
#pragma unroll
    for (int msk = 1; msk < 64; msk <<= 1) sum += __shfl_xor(sum, msk, 64);
    if (lane == 0) pooled[((size_t)b * 256 + c) * 36 + w] = sum * inv;
  }
}

// ---------------------------------------------------------------------------
// K4: implicit-GEMM MFMA conv. Block = (g, b, 2 output rows). 512 thr, 8 waves.
// Accumulate K*K taps x 2 ic-chunks of 16x16x32 MFMAs; A(weights) from L2,
// B(res) from XOR-swizzled LDS tile [8 rows][56 x][64 ic] bf16.
// ---------------------------------------------------------------------------
template <int K>
__device__ __forceinline__ void conv_core(
    const unsigned short* __restrict__ plane,   // resT[b][g]: [2304][64]
    const unsigned short* __restrict__ wTg,     // [K*K][64][64]
    float* __restrict__ outg,                   // convb[b][g*64..][2304]
    unsigned short* lds, int r0, int tid) {
  constexpr int P = K / 2, NR = 2 + 2 * P;
  // zero full tile (halo)
  uint4 zz = {0, 0, 0, 0};
  for (int i = tid; i < 8 * 56 * 8; i += 512) ((uint4*)lds)[i] = zz;
  __syncthreads();
  // stage NR rows x 48 x-positions x 8 ic-octets, swizzled by x-slot
  for (int idx = tid; idx < NR * 384; idx += 512) {
    int i = idx / 384, rem = idx % 384;
    int gx = rem >> 3, o = rem & 7;
    int gy = r0 - P + i;
    if (gy >= 0 && gy < 48) {
      uint4 v = *(const uint4*)(plane + ((size_t)(gy * 48 + gx)) * 64 + o * 8);
      int slot = gx + P;
      *(uint4*)(lds + ((size_t)i * 56 + slot) * 64 + ((o ^ (slot & 7)) * 8)) = v;
    }
  }
  __syncthreads();

  const int w = tid >> 6, lane = tid & 63, lg = lane >> 4, lc = lane & 15;
  const int oc0 = (w >> 1) * 16, ry = w & 1;
  f32x4 acc[3];
  acc[0] = acc[1] = acc[2] = (f32x4){0.f, 0.f, 0.f, 0.f};

  for (int ky = 0; ky < K; ++ky) {
    const unsigned short* rowb = lds + (size_t)(ry + ky) * 56 * 64;
#pragma unroll
    for (int kx = 0; kx < K; ++kx) {
      const int tap = ky * K + kx;
#pragma unroll
      for (int c = 0; c < 2; ++c) {
        short8 aw = *(const short8*)(wTg + (size_t)tap * 4096 + (oc0 + lc) * 64 +
                                     c * 32 + lg * 8);
#pragma unroll
        for (int u = 0; u < 3; ++u) {
          int slot = u * 16 + lc + kx;
          short8 bv = *(const short8*)(rowb + slot * 64 + (((c * 4 + lg) ^ (slot & 7)) * 8));
          acc[u] = __builtin_amdgcn_mfma_f32_16x16x32_bf16(aw, bv, acc[u], 0, 0, 0);
        }
      }
    }
  }
  // D: oc = oc0 + lg*4 + j, px = (r0+ry)*48 + u*16 + lc
#pragma unroll
  for (int u = 0; u < 3; ++u)
#pragma unroll
    for (int j = 0; j < 4; ++j)
      outg[(size_t)(oc0 + lg * 4 + j) * NTOK + (r0 + ry) * 48 + u * 16 + lc] = acc[u][j];
}

__global__ __launch_bounds__(512, 2) void k_conv_mfma(
    const unsigned short* __restrict__ resT, const unsigned short* __restrict__ wT,
    float* __restrict__ convb) {
  __shared__ __align__(16) unsigned short lds[8 * 56 * 64];
  int bid = blockIdx.x;
  int g = bid % 3, sub = bid / 3;
  int b = sub / 24, r0 = (sub % 24) * 2;
  const unsigned short* plane = resT + (((size_t)b * 3 + g) * NTOK) * 64;
  float* outg = convb + ((size_t)b * 192 + g * 64) * NTOK;
  int tid = threadIdx.x;
  if (g == 0)      conv_core<3>(plane, wT,             outg, lds, r0, tid);
  else if (g == 1) conv_core<5>(plane, wT + 9 * 4096,  outg, lds, r0, tid);
  else             conv_core<7>(plane, wT + 34 * 4096, outg, lds, r0, tid);
}

// ---------------------------------------------------------------------------
// K5: combine  pre[b,n,c] = attn_out + q*conv_v + relu(bilinear_upsample(pool))
// ---------------------------------------------------------------------------
__global__ void k_combine(
    const float* __restrict__ qb, const float* __restrict__ accb,
    const float* __restrict__ resb, const float* __restrict__ convb,
    const float* __restrict__ pooled, float* __restrict__ pre) {
  int nt = blockIdx.x;
  int head = blockIdx.y;
  int b = blockIdx.z;
  int tid = threadIdx.x;
  int n = nt * 8 + (tid >> 5);
  int ch = tid & 31;
  int c = head * 32 + ch;
  int g = c >> 6;
  const int sArr[4] = {1, 2, 3, 6};
  int s = sArr[g];

  size_t qidx = (((size_t)b * 8 + head) * NTOK + n) * 32 + ch;
  float qv = qb[qidx];
  float av = accb[qidx];
  float cvv = (g == 0) ? resb[((size_t)b * 256 + c) * NTOK + n]
                       : convb[((size_t)b * 192 + (c - 64)) * NTOK + n];
  const float* pl = pooled + ((size_t)b * 256 + c) * 36;
  float lp;
  if (s == 1) {
    lp = pl[0];
  } else {
    int yy = n / 48, xx = n % 48;
    float fs = (float)(s - 1) / 47.0f;
    float ry = yy * fs, rx = xx * fs;
    int y0 = (int)ry, x0 = (int)rx;
    int y1 = min(y0 + 1, s - 1), x1 = min(x0 + 1, s - 1);
    float wy = ry - (float)y0, wx = rx - (float)x0;
    float v00 = pl[y0 * s + x0], v01 = pl[y0 * s + x1];
    float v10 = pl[y1 * s + x0], v11 = pl[y1 * s + x1];
    lp = v00 * (1 - wy) * (1 - wx) + v01 * (1 - wy) * wx +
         v10 * wy * (1 - wx) + v11 * wy * wx;
  }
  lp = fmaxf(lp, 0.f);
  pre[((size_t)b * NTOK + n) * 256 + c] = av + qv * cvv + lp;
}

// ---------------------------------------------------------------------------
// K6: final projection GEMM  out[9216,256] = pre @ wproj^T + bproj
// ---------------------------------------------------------------------------
__global__ __launch_bounds__(256) void k_gemm_proj(
    const float* __restrict__ pre, const float* __restrict__ wproj,
    const float* __restrict__ bproj, float* __restrict__ outp) {
  __shared__ __align__(16) float xs[128][20];
  __shared__ __align__(16) float ws[128][20];
  const int tid = threadIdx.x;
  const int ty = tid >> 4, tx = tid & 15;
  const int row0 = blockIdx.x * 128;
  const int col0 = blockIdx.y * 128;

  float acc[8][8];
#pragma unroll
  for (int i = 0; i < 8; ++i)
#pragma unroll
    for (int j = 0; j < 8; ++j) acc[i][j] = 0.f;

  for (int kc = 0; kc < 256; kc += 16) {
#pragma unroll
    for (int l = 0; l < 2; ++l) {
      int lin = tid + l * 256;
      int r = lin >> 2, kk = (lin & 3) * 4;
      *(float4*)&xs[r][kk] = *(const float4*)&pre[(size_t)(row0 + r) * 256 + kc + kk];
      *(float4*)&ws[r][kk] = *(const float4*)&wproj[(size_t)(col0 + r) * 256 + kc + kk];
    }
    __syncthreads();
#pragma unroll
    for (int k4 = 0; k4 < 4; ++k4) {
      float4 a4[8], b4[8];
#pragma unroll
      for (int i = 0; i < 8; ++i) a4[i] = *(float4*)&xs[ty + 16 * i][k4 * 4];
#pragma unroll
      for (int j = 0; j < 8; ++j) b4[j] = *(float4*)&ws[tx + 16 * j][k4 * 4];
#pragma unroll
      for (int i = 0; i < 8; ++i)
#pragma unroll
        for (int j = 0; j < 8; ++j)
          acc[i][j] += a4[i].x * b4[j].x + a4[i].y * b4[j].y +
                       a4[i].z * b4[j].z + a4[i].w * b4[j].w;
    }
    __syncthreads();
  }

#pragma unroll
  for (int i = 0; i < 8; ++i) {
    int row = row0 + ty + 16 * i;
#pragma unroll
    for (int j = 0; j < 8; ++j) {
      int col = col0 + tx + 16 * j;
      outp[(size_t)row * 256 + col] = acc[i][j] + bproj[col];
    }
  }
}

// ---------------------------------------------------------------------------
extern "C" void kernel_launch(void* const* d_in, const int* in_sizes, int n_in,
                              void* d_out, int out_size, void* d_ws, size_t ws_size,
                              hipStream_t stream) {
  const float* x     = (const float*)d_in[0];
  const float* wq    = (const float*)d_in[3];
  const float* wkv   = (const float*)d_in[4];
  const float* wres  = (const float*)d_in[5];
  const float* wproj = (const float*)d_in[6];
  const float* bproj = (const float*)d_in[7];
  const float* kern3 = (const float*)d_in[8];
  const float* kern5 = (const float*)d_in[9];
  const float* kern7 = (const float*)d_in[10];

  const size_t SZ = (size_t)4 * 8 * NTOK * 32;   // 2,359,296
  float* wsf  = (float*)d_ws;
  float* qb   = wsf;                              // [0, SZ)
  float* resb = wsf + SZ;                         // [SZ, 2SZ)
  float* accb = wsf + 2 * SZ;                     // [2SZ, 3SZ)
  unsigned short* khi = (unsigned short*)(wsf + 3 * SZ);           // SZ ushorts
  unsigned short* klo = (unsigned short*)(wsf + 3 * SZ + SZ / 2);  // SZ ushorts
  unsigned short* vT  = (unsigned short*)(wsf + 4 * SZ);           // SZ ushorts
  unsigned short* resT = (unsigned short*)(wsf + 4 * SZ + SZ / 2); // 1,769,472 us
  unsigned short* wT   = (unsigned short*)(wsf + 4 * SZ + SZ / 2 + 884736); // 339,968 us
  // dead after attention -> reuse:
  float* convb  = wsf + 3 * SZ;                   // 1,769,472 floats (khi/klo)
  float* pooled = wsf + 4 * SZ;                   // 36,864 floats    (vT)
  // dead after conv -> reuse:
  float* preb   = wsf + 4 * SZ + SZ / 2;          // SZ floats (resT+wT region)
  float* outp = (float*)d_out;

  k_gemm_qkvres<<<dim3(72, 8), 256, 0, stream>>>(x, wq, wkv, wres, qb, khi, klo,
                                                 vT, resb, resT);
  k_wprep<<<dim3(664), 512, 0, stream>>>(kern3, kern5, kern7, wT);
  k_attn_mfma<<<dim3(18, 32), 512, 0, stream>>>(qb, khi, klo, vT, accb);
  k_pool<1><<<dim3(256), 64, 0, stream>>>(resb, pooled);
  k_pool<2><<<dim3(256), 64, 0, stream>>>(resb, pooled);
  k_pool<3><<<dim3(256), 64, 0, stream>>>(resb, pooled);
  k_pool<6><<<dim3(256), 64, 0, stream>>>(resb, pooled);
  k_conv_mfma<<<dim3(288), 512, 0, stream>>>(resT, wT, convb);
  k_combine<<<dim3(288, 8, 4), 256, 0, stream>>>(qb, accb, resb, convb, pooled, preb);
  k_gemm_proj<<<dim3(72, 2), 256, 0, stream>>>(preb, wproj, bproj, outp);
}

// Round 4
// 331.284 us; speedup vs baseline: 5.8550x; 1.5010x over previous
//
#include <hip/hip_runtime.h>
#include <math.h>

#define NTOK 2304   // N = 48*48
#define DIMC 256

typedef __attribute__((ext_vector_type(8))) short short8;
typedef __attribute__((ext_vector_type(4))) float f32x4;

__device__ __forceinline__ unsigned short f2bf(float f) {
  unsigned u = __float_as_uint(f);
  u += 0x7fffu + ((u >> 16) & 1u);
  return (unsigned short)(u >> 16);
}
__device__ __forceinline__ float bf2f(unsigned short h) {
  return __uint_as_float(((unsigned)h) << 16);
}

// ---------------------------------------------------------------------------
// P1: split x -> bf16 hi/lo   (589,824 float4)
// ---------------------------------------------------------------------------
__global__ __launch_bounds__(256) void k_prep_x(
    const float* __restrict__ x, unsigned short* __restrict__ xhi,
    unsigned short* __restrict__ xlo) {
  int i = blockIdx.x * 256 + threadIdx.x;
  float4 v = ((const float4*)x)[i];
  unsigned short h0 = f2bf(v.x), h1 = f2bf(v.y), h2 = f2bf(v.z), h3 = f2bf(v.w);
  unsigned short l0 = f2bf(v.x - bf2f(h0)), l1 = f2bf(v.y - bf2f(h1));
  unsigned short l2 = f2bf(v.z - bf2f(h2)), l3 = f2bf(v.w - bf2f(h3));
  uint2 hp, lp;
  hp.x = (unsigned)h0 | ((unsigned)h1 << 16);
  hp.y = (unsigned)h2 | ((unsigned)h3 << 16);
  lp.x = (unsigned)l0 | ((unsigned)l1 << 16);
  lp.y = (unsigned)l2 | ((unsigned)l3 << 16);
  ((uint2*)xhi)[i] = hp;
  ((uint2*)xlo)[i] = lp;
}

// ---------------------------------------------------------------------------
// P2: split fused W = [wq;wkv;wres] (1024 rows x 256) -> hi/lo
// ---------------------------------------------------------------------------
__global__ __launch_bounds__(256) void k_prep_w(
    const float* __restrict__ wq, const float* __restrict__ wkv,
    const float* __restrict__ wres, unsigned short* __restrict__ Whi,
    unsigned short* __restrict__ Wlo) {
  int idx = blockIdx.x * 256 + threadIdx.x;   // 65536 float4s
  int row = idx >> 6, q4 = idx & 63;
  const float* src;
  if (row < 256)      src = wq + (size_t)row * 256;
  else if (row < 768) src = wkv + (size_t)(row - 256) * 256;
  else                src = wres + (size_t)(row - 768) * 256;
  float4 v = *(const float4*)(src + q4 * 4);
  unsigned short h0 = f2bf(v.x), h1 = f2bf(v.y), h2 = f2bf(v.z), h3 = f2bf(v.w);
  unsigned short l0 = f2bf(v.x - bf2f(h0)), l1 = f2bf(v.y - bf2f(h1));
  unsigned short l2 = f2bf(v.z - bf2f(h2)), l3 = f2bf(v.w - bf2f(h3));
  uint2 hp, lp;
  hp.x = (unsigned)h0 | ((unsigned)h1 << 16);
  hp.y = (unsigned)h2 | ((unsigned)h3 << 16);
  lp.x = (unsigned)l0 | ((unsigned)l1 << 16);
  lp.y = (unsigned)l2 | ((unsigned)l3 << 16);
  ((uint2*)Whi)[idx] = hp;
  ((uint2*)Wlo)[idx] = lp;
}

// ---------------------------------------------------------------------------
// P3: split wproj (256x256) -> hi/lo (launched after attention; lives in vT slack)
// ---------------------------------------------------------------------------
__global__ __launch_bounds__(256) void k_prep_wproj(
    const float* __restrict__ wproj, unsigned short* __restrict__ pwhi,
    unsigned short* __restrict__ pwlo) {
  int idx = blockIdx.x * 256 + threadIdx.x;   // 16384 float4s
  float4 v = ((const float4*)wproj)[idx];
  unsigned short h0 = f2bf(v.x), h1 = f2bf(v.y), h2 = f2bf(v.z), h3 = f2bf(v.w);
  unsigned short l0 = f2bf(v.x - bf2f(h0)), l1 = f2bf(v.y - bf2f(h1));
  unsigned short l2 = f2bf(v.z - bf2f(h2)), l3 = f2bf(v.w - bf2f(h3));
  uint2 hp, lp;
  hp.x = (unsigned)h0 | ((unsigned)h1 << 16);
  hp.y = (unsigned)h2 | ((unsigned)h3 << 16);
  lp.x = (unsigned)l0 | ((unsigned)l1 << 16);
  lp.y = (unsigned)l2 | ((unsigned)l3 << 16);
  ((uint2*)pwhi)[idx] = hp;
  ((uint2*)pwlo)[idx] = lp;
}

// ---------------------------------------------------------------------------
// K1: MFMA split-bf16 fused GEMM  Y[9216,1024] = X @ W^T, scatter epilogue.
// 128x128 tile, 512 thr (8 waves 4x2), BK=64, XOR-octet-swizzled LDS.
// ---------------------------------------------------------------------------
__global__ __launch_bounds__(512, 2) void k_gemm_qkvres_mfma(
    const unsigned short* __restrict__ xhi, const unsigned short* __restrict__ xlo,
    const unsigned short* __restrict__ Whi, const unsigned short* __restrict__ Wlo,
    float* __restrict__ qb, unsigned short* __restrict__ khi,
    unsigned short* __restrict__ klo, unsigned short* __restrict__ vT,
    float* __restrict__ resb, unsigned short* __restrict__ resT) {
  __shared__ __align__(16) unsigned short Ah[128 * 64];
  __shared__ __align__(16) unsigned short Al[128 * 64];
  __shared__ __align__(16) unsigned short Bh[128 * 64];
  __shared__ __align__(16) unsigned short Bl[128 * 64];
  const int tid = threadIdx.x;
  const int row0 = blockIdx.x * 128;
  const int col0 = blockIdx.y * 128;
  const int w = tid >> 6, lane = tid & 63, lg = lane >> 4, lc = lane & 15;
  const int wm = w >> 1, wn = w & 1;

  f32x4 acc[2][4];
#pragma unroll
  for (int i = 0; i < 2; ++i)
#pragma unroll
    for (int j = 0; j < 4; ++j) acc[i][j] = (f32x4){0.f, 0.f, 0.f, 0.f};

  for (int kc = 0; kc < 256; kc += 64) {
    __syncthreads();
#pragma unroll
    for (int l = 0; l < 2; ++l) {
      int idx = tid + l * 512;
      int r = idx >> 3, o = idx & 7;
      int sl = ((o ^ (r & 7))) * 8;
      *(uint4*)&Ah[r * 64 + sl] = *(const uint4*)&xhi[(size_t)(row0 + r) * 256 + kc + o * 8];
      *(uint4*)&Al[r * 64 + sl] = *(const uint4*)&xlo[(size_t)(row0 + r) * 256 + kc + o * 8];
      *(uint4*)&Bh[r * 64 + sl] = *(const uint4*)&Whi[(size_t)(col0 + r) * 256 + kc + o * 8];
      *(uint4*)&Bl[r * 64 + sl] = *(const uint4*)&Wlo[(size_t)(col0 + r) * 256 + kc + o * 8];
    }
    __syncthreads();
#pragma unroll
    for (int ks = 0; ks < 2; ++ks) {
      short8 ah[2], al[2], bh[4], bl[4];
#pragma unroll
      for (int mi = 0; mi < 2; ++mi) {
        int r = wm * 32 + mi * 16 + lc;
        int sl = (((ks * 4 + lg) ^ (r & 7))) * 8;
        ah[mi] = *(short8*)&Ah[r * 64 + sl];
        al[mi] = *(short8*)&Al[r * 64 + sl];
      }
#pragma unroll
      for (int ni = 0; ni < 4; ++ni) {
        int r = wn * 64 + ni * 16 + lc;
        int sl = (((ks * 4 + lg) ^ (r & 7))) * 8;
        bh[ni] = *(short8*)&Bh[r * 64 + sl];
        bl[ni] = *(short8*)&Bl[r * 64 + sl];
      }
#pragma unroll
      for (int mi = 0; mi < 2; ++mi)
#pragma unroll
        for (int ni = 0; ni < 4; ++ni) {
          acc[mi][ni] = __builtin_amdgcn_mfma_f32_16x16x32_bf16(ah[mi], bh[ni], acc[mi][ni], 0, 0, 0);
          acc[mi][ni] = __builtin_amdgcn_mfma_f32_16x16x32_bf16(ah[mi], bl[ni], acc[mi][ni], 0, 0, 0);
          acc[mi][ni] = __builtin_amdgcn_mfma_f32_16x16x32_bf16(al[mi], bh[ni], acc[mi][ni], 0, 0, 0);
        }
    }
  }

  // epilogue scatter (D: row = m-frag + lg*4+j, col = n-frag + lc)
#pragma unroll
  for (int mi = 0; mi < 2; ++mi) {
    int rbase = row0 + wm * 32 + mi * 16 + lg * 4;
#pragma unroll
    for (int ni = 0; ni < 4; ++ni) {
      int col = col0 + wn * 64 + ni * 16 + lc;
#pragma unroll
      for (int j = 0; j < 4; ++j) {
        int row = rbase + j;
        int b = row / NTOK, n = row % NTOK;
        float vv = acc[mi][ni][j];
        if (col < 256) {
          int head = col >> 5, ch = col & 31;
          qb[(((size_t)b * 8 + head) * NTOK + n) * 32 + ch] = vv;
        } else if (col < 512) {
          int o = col - 256; int head = o >> 5, ch = o & 31;
          size_t idx = (((size_t)b * 8 + head) * NTOK + n) * 32 + ch;
          unsigned short h = f2bf(vv);
          khi[idx] = h;
          klo[idx] = f2bf(vv - bf2f(h));
        } else if (col < 768) {
          int o = col - 512; int head = o >> 5, ch = o & 31;
          vT[(((size_t)b * 8 + head) * 32 + ch) * NTOK + n] = f2bf(vv);
        } else {
          int c = col - 768;
          float rv = fmaxf(vv, 0.f);
          resb[((size_t)b * 256 + c) * NTOK + n] = rv;
          if (c >= 64) {
            int g = (c >> 6) - 1, ic = c & 63;
            resT[(((size_t)b * 3 + g) * NTOK + n) * 64 + ic] = f2bf(rv);
          }
        }
      }
    }
  }
}

// ---------------------------------------------------------------------------
// K1b: constrained conv weights -> bf16  wT[(tapbase+t)*4096 + oc*64 + ic]
// ---------------------------------------------------------------------------
__global__ void k_wprep(const float* __restrict__ k3, const float* __restrict__ k5,
                        const float* __restrict__ k7, unsigned short* __restrict__ wT) {
  int idx = blockIdx.x * 512 + threadIdx.x;
  if (idx >= 83 * 4096) return;
  const float* src; int K, tloc;
  if (idx < 9 * 4096)       { K = 3; src = k3; tloc = idx >> 12; }
  else if (idx < 34 * 4096) { K = 5; src = k5; tloc = (idx - 9 * 4096) >> 12; }
  else                      { K = 7; src = k7; tloc = (idx - 34 * 4096) >> 12; }
  int r = idx & 4095, oc = r >> 6, ic = r & 63;
  int K2 = K * K, ctr = K2 / 2;
  float v = (tloc == ctr) ? -1.f
          : src[((size_t)oc * 64 + ic) * (K2 - 1) + (tloc < ctr ? tloc : tloc - 1)];
  wT[idx] = f2bf(v);
}

// ---------------------------------------------------------------------------
// K2: MFMA flash attention (unchanged)
// ---------------------------------------------------------------------------
__global__ __launch_bounds__(512, 4) void k_attn_mfma(
    const float* __restrict__ qb, const unsigned short* __restrict__ khi,
    const unsigned short* __restrict__ klo, const unsigned short* __restrict__ vT,
    float* __restrict__ accb) {
  const int bh = blockIdx.y;
  const int r0 = blockIdx.x * 128;
  const int tid = threadIdx.x;
  const int w = tid >> 6;
  const int lane = tid & 63;
  const int lg = lane >> 4;
  const int lc = lane & 15;

  __shared__ __align__(16) unsigned short ks_hi[64][40];
  __shared__ __align__(16) unsigned short ks_lo[64][40];
  __shared__ __align__(16) unsigned short vs[32][72];
  __shared__ __align__(16) unsigned short ps[8][16][72];

  const float scale = 0.17677669529663688f;

  const float* qp = qb + (((size_t)bh * NTOK + r0 + w * 16 + lc) * 32 + lg * 8);
  float qf[8];
  *(float4*)&qf[0] = *(const float4*)qp;
  *(float4*)&qf[4] = *(const float4*)(qp + 4);
  short8 qh, ql;
#pragma unroll
  for (int i = 0; i < 8; ++i) {
    float v = qf[i] * scale;
    unsigned short h = f2bf(v);
    qh[i] = (short)h;
    ql[i] = (short)f2bf(v - bf2f(h));
  }

  float m_r[4], l_r[4];
#pragma unroll
  for (int j = 0; j < 4; ++j) { m_r[j] = -3.0e38f; l_r[j] = 0.f; }
  f32x4 o0 = {0.f, 0.f, 0.f, 0.f};
  f32x4 o1 = {0.f, 0.f, 0.f, 0.f};

  const int srow = tid >> 3, sq8 = tid & 7;
  const int vrow = tid >> 4, vp = tid & 15;

  for (int kt = 0; kt < 36; ++kt) {
    const int kv0 = kt * 64;
    __syncthreads();
    *(uint2*)&ks_hi[srow][sq8 * 4] =
        *(const uint2*)(khi + ((size_t)bh * NTOK + kv0 + srow) * 32 + sq8 * 4);
    *(uint2*)&ks_lo[srow][sq8 * 4] =
        *(const uint2*)(klo + ((size_t)bh * NTOK + kv0 + srow) * 32 + sq8 * 4);
    *(uint2*)&vs[vrow][vp * 4] =
        *(const uint2*)(vT + ((size_t)bh * 32 + vrow) * NTOK + kv0 + vp * 4);
    __syncthreads();

    f32x4 s[4];
#pragma unroll
    for (int nt = 0; nt < 4; ++nt) {
      short8 kh = *(short8*)&ks_hi[lc + 16 * nt][lg * 8];
      short8 kl = *(short8*)&ks_lo[lc + 16 * nt][lg * 8];
      f32x4 a = {0.f, 0.f, 0.f, 0.f};
      a = __builtin_amdgcn_mfma_f32_16x16x32_bf16(qh, kh, a, 0, 0, 0);
      a = __builtin_amdgcn_mfma_f32_16x16x32_bf16(qh, kl, a, 0, 0, 0);
      a = __builtin_amdgcn_mfma_f32_16x16x32_bf16(ql, kh, a, 0, 0, 0);
      s[nt] = a;
    }

#pragma unroll
    for (int j = 0; j < 4; ++j) {
      float mt = fmaxf(fmaxf(s[0][j], s[1][j]), fmaxf(s[2][j], s[3][j]));
#pragma unroll
      for (int msk = 1; msk < 16; msk <<= 1) mt = fmaxf(mt, __shfl_xor(mt, msk, 64));
      float mn = fmaxf(m_r[j], mt);
      float corr = __expf(m_r[j] - mn);
      m_r[j] = mn;
      float ls = 0.f;
#pragma unroll
      for (int nt = 0; nt < 4; ++nt) {
        float p = __expf(s[nt][j] - mn);
        s[nt][j] = p;
        ls += p;
      }
#pragma unroll
      for (int msk = 1; msk < 16; msk <<= 1) ls += __shfl_xor(ls, msk, 64);
      l_r[j] = l_r[j] * corr + ls;
      o0[j] *= corr;
      o1[j] *= corr;
    }

#pragma unroll
    for (int nt = 0; nt < 4; ++nt)
#pragma unroll
      for (int j = 0; j < 4; ++j)
        ps[w][lg * 4 + j][nt * 16 + lc] = f2bf(s[nt][j]);

    __builtin_amdgcn_sched_barrier(0);
    asm volatile("s_waitcnt lgkmcnt(0)" ::: "memory");
    __builtin_amdgcn_sched_barrier(0);

#pragma unroll
    for (int h2 = 0; h2 < 2; ++h2) {
      short8 pa = *(short8*)&ps[w][lc][h2 * 32 + lg * 8];
      short8 v0 = *(short8*)&vs[lc][h2 * 32 + lg * 8];
      short8 v1 = *(short8*)&vs[lc + 16][h2 * 32 + lg * 8];
      o0 = __builtin_amdgcn_mfma_f32_16x16x32_bf16(pa, v0, o0, 0, 0, 0);
      o1 = __builtin_amdgcn_mfma_f32_16x16x32_bf16(pa, v1, o1, 0, 0, 0);
    }
  }

  float* op = accb + ((size_t)bh * NTOK + r0 + w * 16) * 32;
#pragma unroll
  for (int j = 0; j < 4; ++j) {
    float inv = 1.f / l_r[j];
    int r = lg * 4 + j;
    op[r * 32 + lc] = o0[j] * inv;
    op[r * 32 + lc + 16] = o1[j] * inv;
  }
}

// ---------------------------------------------------------------------------
// K3: avg-pool per (b, channel)
// ---------------------------------------------------------------------------
template <int S>
__global__ void k_pool(const float* __restrict__ resb, float* __restrict__ pooled) {
  constexpr int G = (S == 1) ? 0 : (S == 2) ? 1 : (S == 3) ? 2 : 3;
  constexpr int WSZ = 48 / S;
  constexpr int NPX = WSZ * WSZ;
  int bi = blockIdx.x;
  int b = bi >> 6, cc = bi & 63;
  int c = G * 64 + cc;
  int lane = threadIdx.x;
  const float* src = resb + ((size_t)b * 256 + c) * NTOK;
  const float inv = 1.f / NPX;
  for (int w = 0; w < S * S; ++w) {
    int wy = w / S, wx = w % S;
    float sum = 0.f;
    for (int idx = lane; idx < NPX; idx += 64) {
      int yy = wy * WSZ + idx / WSZ;
      int xx = wx * WSZ + idx % WSZ;
      sum += src[yy * 48 + xx];
    }
#pragma unroll
    for (int msk = 1; msk < 64; msk <<= 1) sum += __shfl_xor(sum, msk, 64);
    if (lane == 0) pooled[((size_t)b * 256 + c) * 36 + w] = sum * inv;
  }
}

// ---------------------------------------------------------------------------
// K4: implicit-GEMM MFMA conv (unchanged)
// ---------------------------------------------------------------------------
template <int K>
__device__ __forceinline__ void conv_core(
    const unsigned short* __restrict__ plane,
    const unsigned short* __restrict__ wTg,
    float* __restrict__ outg,
    unsigned short* lds, int r0, int tid) {
  constexpr int P = K / 2, NR = 2 + 2 * P;
  uint4 zz = {0, 0, 0, 0};
  for (int i = tid; i < 8 * 56 * 8; i += 512) ((uint4*)lds)[i] = zz;
  __syncthreads();
  for (int idx = tid; idx < NR * 384; idx += 512) {
    int i = idx / 384, rem = idx % 384;
    int gx = rem >> 3, o = rem & 7;
    int gy = r0 - P + i;
    if (gy >= 0 && gy < 48) {
      uint4 v = *(const uint4*)(plane + ((size_t)(gy * 48 + gx)) * 64 + o * 8);
      int slot = gx + P;
      *(uint4*)(lds + ((size_t)i * 56 + slot) * 64 + ((o ^ (slot & 7)) * 8)) = v;
    }
  }
  __syncthreads();

  const int w = tid >> 6, lane = tid & 63, lg = lane >> 4, lc = lane & 15;
  const int oc0 = (w >> 1) * 16, ry = w & 1;
  f32x4 acc[3];
  acc[0] = acc[1] = acc[2] = (f32x4){0.f, 0.f, 0.f, 0.f};

  for (int ky = 0; ky < K; ++ky) {
    const unsigned short* rowb = lds + (size_t)(ry + ky) * 56 * 64;
#pragma unroll
    for (int kx = 0; kx < K; ++kx) {
      const int tap = ky * K + kx;
#pragma unroll
      for (int c = 0; c < 2; ++c) {
        short8 aw = *(const short8*)(wTg + (size_t)tap * 4096 + (oc0 + lc) * 64 +
                                     c * 32 + lg * 8);
#pragma unroll
        for (int u = 0; u < 3; ++u) {
          int slot = u * 16 + lc + kx;
          short8 bv = *(const short8*)(rowb + slot * 64 + (((c * 4 + lg) ^ (slot & 7)) * 8));
          acc[u] = __builtin_amdgcn_mfma_f32_16x16x32_bf16(aw, bv, acc[u], 0, 0, 0);
        }
      }
    }
  }
#pragma unroll
  for (int u = 0; u < 3; ++u)
#pragma unroll
    for (int j = 0; j < 4; ++j)
      outg[(size_t)(oc0 + lg * 4 + j) * NTOK + (r0 + ry) * 48 + u * 16 + lc] = acc[u][j];
}

__global__ __launch_bounds__(512, 2) void k_conv_mfma(
    const unsigned short* __restrict__ resT, const unsigned short* __restrict__ wT,
    float* __restrict__ convb) {
  __shared__ __align__(16) unsigned short lds[8 * 56 * 64];
  int bid = blockIdx.x;
  int g = bid % 3, sub = bid / 3;
  int b = sub / 24, r0 = (sub % 24) * 2;
  const unsigned short* plane = resT + (((size_t)b * 3 + g) * NTOK) * 64;
  float* outg = convb + ((size_t)b * 192 + g * 64) * NTOK;
  int tid = threadIdx.x;
  if (g == 0)      conv_core<3>(plane, wT,             outg, lds, r0, tid);
  else if (g == 1) conv_core<5>(plane, wT + 9 * 4096,  outg, lds, r0, tid);
  else             conv_core<7>(plane, wT + 34 * 4096, outg, lds, r0, tid);
}

// ---------------------------------------------------------------------------
// K5: combine -> pre as bf16 hi/lo
// ---------------------------------------------------------------------------
__global__ void k_combine(
    const float* __restrict__ qb, const float* __restrict__ accb,
    const float* __restrict__ resb, const float* __restrict__ convb,
    const float* __restrict__ pooled, unsigned short* __restrict__ preh,
    unsigned short* __restrict__ prel) {
  int nt = blockIdx.x;
  int head = blockIdx.y;
  int b = blockIdx.z;
  int tid = threadIdx.x;
  int n = nt * 8 + (tid >> 5);
  int ch = tid & 31;
  int c = head * 32 + ch;
  int g = c >> 6;
  const int sArr[4] = {1, 2, 3, 6};
  int s = sArr[g];

  size_t qidx = (((size_t)b * 8 + head) * NTOK + n) * 32 + ch;
  float qv = qb[qidx];
  float av = accb[qidx];
  float cvv = (g == 0) ? resb[((size_t)b * 256 + c) * NTOK + n]
                       : convb[((size_t)b * 192 + (c - 64)) * NTOK + n];
  const float* pl = pooled + ((size_t)b * 256 + c) * 36;
  float lp;
  if (s == 1) {
    lp = pl[0];
  } else {
    int yy = n / 48, xx = n % 48;
    float fs = (float)(s - 1) / 47.0f;
    float ry = yy * fs, rx = xx * fs;
    int y0 = (int)ry, x0 = (int)rx;
    int y1 = min(y0 + 1, s - 1), x1 = min(x0 + 1, s - 1);
    float wy = ry - (float)y0, wx = rx - (float)x0;
    float v00 = pl[y0 * s + x0], v01 = pl[y0 * s + x1];
    float v10 = pl[y1 * s + x0], v11 = pl[y1 * s + x1];
    lp = v00 * (1 - wy) * (1 - wx) + v01 * (1 - wy) * wx +
         v10 * wy * (1 - wx) + v11 * wy * wx;
  }
  lp = fmaxf(lp, 0.f);
  float val = av + qv * cvv + lp;
  unsigned short h = f2bf(val);
  size_t oidx = ((size_t)b * NTOK + n) * 256 + c;
  preh[oidx] = h;
  prel[oidx] = f2bf(val - bf2f(h));
}

// ---------------------------------------------------------------------------
// K6: MFMA split-bf16 projection GEMM  out = pre @ wproj^T + bproj
// ---------------------------------------------------------------------------
__global__ __launch_bounds__(512, 2) void k_gemm_proj_mfma(
    const unsigned short* __restrict__ preh, const unsigned short* __restrict__ prel,
    const unsigned short* __restrict__ pwhi, const unsigned short* __restrict__ pwlo,
    const float* __restrict__ bproj, float* __restrict__ outp) {
  __shared__ __align__(16) unsigned short Ah[128 * 64];
  __shared__ __align__(16) unsigned short Al[128 * 64];
  __shared__ __align__(16) unsigned short Bh[128 * 64];
  __shared__ __align__(16) unsigned short Bl[128 * 64];
  const int tid = threadIdx.x;
  const int row0 = blockIdx.x * 128;
  const int col0 = blockIdx.y * 128;
  const int w = tid >> 6, lane = tid & 63, lg = lane >> 4, lc = lane & 15;
  const int wm = w >> 1, wn = w & 1;

  f32x4 acc[2][4];
#pragma unroll
  for (int i = 0; i < 2; ++i)
#pragma unroll
    for (int j = 0; j < 4; ++j) acc[i][j] = (f32x4){0.f, 0.f, 0.f, 0.f};

  for (int kc = 0; kc < 256; kc += 64) {
    __syncthreads();
#pragma unroll
    for (int l = 0; l < 2; ++l) {
      int idx = tid + l * 512;
      int r = idx >> 3, o = idx & 7;
      int sl = ((o ^ (r & 7))) * 8;
      *(uint4*)&Ah[r * 64 + sl] = *(const uint4*)&preh[(size_t)(row0 + r) * 256 + kc + o * 8];
      *(uint4*)&Al[r * 64 + sl] = *(const uint4*)&prel[(size_t)(row0 + r) * 256 + kc + o * 8];
      *(uint4*)&Bh[r * 64 + sl] = *(const uint4*)&pwhi[(size_t)(col0 + r) * 256 + kc + o * 8];
      *(uint4*)&Bl[r * 64 + sl] = *(const uint4*)&pwlo[(size_t)(col0 + r) * 256 + kc + o * 8];
    }
    __syncthreads();
#pragma unroll
    for (int ks = 0; ks < 2; ++ks) {
      short8 ah[2], al[2], bh[4], bl[4];
#pragma unroll
      for (int mi = 0; mi < 2; ++mi) {
        int r = wm * 32 + mi * 16 + lc;
        int sl = (((ks * 4 + lg) ^ (r & 7))) * 8;
        ah[mi] = *(short8*)&Ah[r * 64 + sl];
        al[mi] = *(short8*)&Al[r * 64 + sl];
      }
#pragma unroll
      for (int ni = 0; ni < 4; ++ni) {
        int r = wn * 64 + ni * 16 + lc;
        int sl = (((ks * 4 + lg) ^ (r & 7))) * 8;
        bh[ni] = *(short8*)&Bh[r * 64 + sl];
        bl[ni] = *(short8*)&Bl[r * 64 + sl];
      }
#pragma unroll
      for (int mi = 0; mi < 2; ++mi)
#pragma unroll
        for (int ni = 0; ni < 4; ++ni) {
          acc[mi][ni] = __builtin_amdgcn_mfma_f32_16x16x32_bf16(ah[mi], bh[ni], acc[mi][ni], 0, 0, 0);
          acc[mi][ni] = __builtin_amdgcn_mfma_f32_16x16x32_bf16(ah[mi], bl[ni], acc[mi][ni], 0, 0, 0);
          acc[mi][ni] = __builtin_amdgcn_mfma_f32_16x16x32_bf16(al[mi], bh[ni], acc[mi][ni], 0, 0, 0);
        }
    }
  }

#pragma unroll
  for (int mi = 0; mi < 2; ++mi) {
    int rbase = row0 + wm * 32 + mi * 16 + lg * 4;
#pragma unroll
    for (int ni = 0; ni < 4; ++ni) {
      int col = col0 + wn * 64 + ni * 16 + lc;
#pragma unroll
      for (int j = 0; j < 4; ++j)
        outp[(size_t)(rbase + j) * 256 + col] = acc[mi][ni][j] + bproj[col];
    }
  }
}

// ---------------------------------------------------------------------------
extern "C" void kernel_launch(void* const* d_in, const int* in_sizes, int n_in,
                              void* d_out, int out_size, void* d_ws, size_t ws_size,
                              hipStream_t stream) {
  const float* x     = (const float*)d_in[0];
  const float* wq    = (const float*)d_in[3];
  const float* wkv   = (const float*)d_in[4];
  const float* wres  = (const float*)d_in[5];
  const float* wproj = (const float*)d_in[6];
  const float* bproj = (const float*)d_in[7];
  const float* kern3 = (const float*)d_in[8];
  const float* kern5 = (const float*)d_in[9];
  const float* kern7 = (const float*)d_in[10];

  const size_t SZ = (size_t)4 * 8 * NTOK * 32;   // 2,359,296
  float* wsf  = (float*)d_ws;
  float* qb   = wsf;                              // [0, SZ)
  float* resb = wsf + SZ;                         // [SZ, 2SZ)
  float* accb = wsf + 2 * SZ;                     // [2SZ, 3SZ)
  // xhi/xlo overlay accb (x dead before attention writes accb)
  unsigned short* xhi = (unsigned short*)(wsf + 2 * SZ);           // SZ us
  unsigned short* xlo = (unsigned short*)(wsf + 2 * SZ + SZ / 2);  // SZ us
  unsigned short* khi = (unsigned short*)(wsf + 3 * SZ);           // SZ us
  unsigned short* klo = (unsigned short*)(wsf + 3 * SZ + SZ / 2);  // SZ us
  unsigned short* vT  = (unsigned short*)(wsf + 4 * SZ);           // SZ us
  unsigned short* resT = (unsigned short*)(wsf + 4 * SZ + SZ / 2); // 1,769,472 us
  unsigned short* wT   = (unsigned short*)(wsf + 4 * SZ + SZ / 2 + 884736); // 339,968 us
  // Whi/Wlo live only during qkvres gemm; overlay future preh/prel tail
  unsigned short* Whi = (unsigned short*)(wsf + 4 * SZ + SZ / 2 + 884736 + 169984);
  unsigned short* Wlo = Whi + 262144;             // ends < 5.5 SZ
  // reuse after attention:
  float* convb  = wsf + 3 * SZ;                   // overlay khi/klo
  float* pooled = wsf + 4 * SZ;                   // overlay vT (36,864 floats)
  unsigned short* pwhi = (unsigned short*)(wsf + 4 * SZ + 40960);  // vT slack
  unsigned short* pwlo = pwhi + 65536;
  // pre hi/lo overlay resT/wT/Whi region (all dead before combine)
  unsigned short* preh = (unsigned short*)(wsf + 4 * SZ + SZ / 2); // SZ us
  unsigned short* prel = (unsigned short*)(wsf + 5 * SZ);          // SZ us
  float* outp = (float*)d_out;

  k_prep_x<<<dim3(2304), 256, 0, stream>>>(x, xhi, xlo);
  k_prep_w<<<dim3(256), 256, 0, stream>>>(wq, wkv, wres, Whi, Wlo);
  k_wprep<<<dim3(664), 512, 0, stream>>>(kern3, kern5, kern7, wT);
  k_gemm_qkvres_mfma<<<dim3(72, 8), 512, 0, stream>>>(xhi, xlo, Whi, Wlo, qb, khi,
                                                      klo, vT, resb, resT);
  k_attn_mfma<<<dim3(18, 32), 512, 0, stream>>>(qb, khi, klo, vT, accb);
  k_pool<1><<<dim3(256), 64, 0, stream>>>(resb, pooled);
  k_pool<2><<<dim3(256), 64, 0, stream>>>(resb, pooled);
  k_pool<3><<<dim3(256), 64, 0, stream>>>(resb, pooled);
  k_pool<6><<<dim3(256), 64, 0, stream>>>(resb, pooled);
  k_prep_wproj<<<dim3(64), 256, 0, stream>>>(wproj, pwhi, pwlo);
  k_conv_mfma<<<dim3(288), 512, 0, stream>>>(resT, wT, convb);
  k_combine<<<dim3(288, 8, 4), 256, 0, stream>>>(qb, accb, resb, convb, pooled,
                                                 preh, prel);
  k_gemm_proj_mfma<<<dim3(72, 2), 512, 0, stream>>>(preh, prel, pwhi, pwlo, bproj, outp);
}

// Round 5
// 307.655 us; speedup vs baseline: 6.3047x; 1.0768x over previous
//
#include <hip/hip_runtime.h>
#include <math.h>

#define NTOK 2304   // N = 48*48
#define DIMC 256

typedef __attribute__((ext_vector_type(8))) short short8;
typedef __attribute__((ext_vector_type(4))) float f32x4;

__device__ __forceinline__ unsigned short f2bf(float f) {
  unsigned u = __float_as_uint(f);
  u += 0x7fffu + ((u >> 16) & 1u);
  return (unsigned short)(u >> 16);
}
__device__ __forceinline__ float bf2f(unsigned short h) {
  return __uint_as_float(((unsigned)h) << 16);
}

// ---------------------------------------------------------------------------
// P1: split x -> bf16 hi/lo
// ---------------------------------------------------------------------------
__global__ __launch_bounds__(256) void k_prep_x(
    const float* __restrict__ x, unsigned short* __restrict__ xhi,
    unsigned short* __restrict__ xlo) {
  int i = blockIdx.x * 256 + threadIdx.x;
  float4 v = ((const float4*)x)[i];
  unsigned short h0 = f2bf(v.x), h1 = f2bf(v.y), h2 = f2bf(v.z), h3 = f2bf(v.w);
  unsigned short l0 = f2bf(v.x - bf2f(h0)), l1 = f2bf(v.y - bf2f(h1));
  unsigned short l2 = f2bf(v.z - bf2f(h2)), l3 = f2bf(v.w - bf2f(h3));
  uint2 hp, lp;
  hp.x = (unsigned)h0 | ((unsigned)h1 << 16);
  hp.y = (unsigned)h2 | ((unsigned)h3 << 16);
  lp.x = (unsigned)l0 | ((unsigned)l1 << 16);
  lp.y = (unsigned)l2 | ((unsigned)l3 << 16);
  ((uint2*)xhi)[i] = hp;
  ((uint2*)xlo)[i] = lp;
}

// ---------------------------------------------------------------------------
// P2: split fused W = [wq;wkv;wres] -> hi/lo
// ---------------------------------------------------------------------------
__global__ __launch_bounds__(256) void k_prep_w(
    const float* __restrict__ wq, const float* __restrict__ wkv,
    const float* __restrict__ wres, unsigned short* __restrict__ Whi,
    unsigned short* __restrict__ Wlo) {
  int idx = blockIdx.x * 256 + threadIdx.x;
  int row = idx >> 6, q4 = idx & 63;
  const float* src;
  if (row < 256)      src = wq + (size_t)row * 256;
  else if (row < 768) src = wkv + (size_t)(row - 256) * 256;
  else                src = wres + (size_t)(row - 768) * 256;
  float4 v = *(const float4*)(src + q4 * 4);
  unsigned short h0 = f2bf(v.x), h1 = f2bf(v.y), h2 = f2bf(v.z), h3 = f2bf(v.w);
  unsigned short l0 = f2bf(v.x - bf2f(h0)), l1 = f2bf(v.y - bf2f(h1));
  unsigned short l2 = f2bf(v.z - bf2f(h2)), l3 = f2bf(v.w - bf2f(h3));
  uint2 hp, lp;
  hp.x = (unsigned)h0 | ((unsigned)h1 << 16);
  hp.y = (unsigned)h2 | ((unsigned)h3 << 16);
  lp.x = (unsigned)l0 | ((unsigned)l1 << 16);
  lp.y = (unsigned)l2 | ((unsigned)l3 << 16);
  ((uint2*)Whi)[idx] = hp;
  ((uint2*)Wlo)[idx] = lp;
}

// ---------------------------------------------------------------------------
// P3: split wproj -> hi/lo
// ---------------------------------------------------------------------------
__global__ __launch_bounds__(256) void k_prep_wproj(
    const float* __restrict__ wproj, unsigned short* __restrict__ pwhi,
    unsigned short* __restrict__ pwlo) {
  int idx = blockIdx.x * 256 + threadIdx.x;
  float4 v = ((const float4*)wproj)[idx];
  unsigned short h0 = f2bf(v.x), h1 = f2bf(v.y), h2 = f2bf(v.z), h3 = f2bf(v.w);
  unsigned short l0 = f2bf(v.x - bf2f(h0)), l1 = f2bf(v.y - bf2f(h1));
  unsigned short l2 = f2bf(v.z - bf2f(h2)), l3 = f2bf(v.w - bf2f(h3));
  uint2 hp, lp;
  hp.x = (unsigned)h0 | ((unsigned)h1 << 16);
  hp.y = (unsigned)h2 | ((unsigned)h3 << 16);
  lp.x = (unsigned)l0 | ((unsigned)l1 << 16);
  lp.y = (unsigned)l2 | ((unsigned)l3 << 16);
  ((uint2*)pwhi)[idx] = hp;
  ((uint2*)pwlo)[idx] = lp;
}

// ---------------------------------------------------------------------------
// K1: MFMA split-bf16 fused GEMM (unchanged from round 3)
// ---------------------------------------------------------------------------
__global__ __launch_bounds__(512, 2) void k_gemm_qkvres_mfma(
    const unsigned short* __restrict__ xhi, const unsigned short* __restrict__ xlo,
    const unsigned short* __restrict__ Whi, const unsigned short* __restrict__ Wlo,
    float* __restrict__ qb, unsigned short* __restrict__ khi,
    unsigned short* __restrict__ klo, unsigned short* __restrict__ vT,
    float* __restrict__ resb, unsigned short* __restrict__ resT) {
  __shared__ __align__(16) unsigned short Ah[128 * 64];
  __shared__ __align__(16) unsigned short Al[128 * 64];
  __shared__ __align__(16) unsigned short Bh[128 * 64];
  __shared__ __align__(16) unsigned short Bl[128 * 64];
  const int tid = threadIdx.x;
  const int row0 = blockIdx.x * 128;
  const int col0 = blockIdx.y * 128;
  const int w = tid >> 6, lane = tid & 63, lg = lane >> 4, lc = lane & 15;
  const int wm = w >> 1, wn = w & 1;

  f32x4 acc[2][4];
#pragma unroll
  for (int i = 0; i < 2; ++i)
#pragma unroll
    for (int j = 0; j < 4; ++j) acc[i][j] = (f32x4){0.f, 0.f, 0.f, 0.f};

  for (int kc = 0; kc < 256; kc += 64) {
    __syncthreads();
#pragma unroll
    for (int l = 0; l < 2; ++l) {
      int idx = tid + l * 512;
      int r = idx >> 3, o = idx & 7;
      int sl = ((o ^ (r & 7))) * 8;
      *(uint4*)&Ah[r * 64 + sl] = *(const uint4*)&xhi[(size_t)(row0 + r) * 256 + kc + o * 8];
      *(uint4*)&Al[r * 64 + sl] = *(const uint4*)&xlo[(size_t)(row0 + r) * 256 + kc + o * 8];
      *(uint4*)&Bh[r * 64 + sl] = *(const uint4*)&Whi[(size_t)(col0 + r) * 256 + kc + o * 8];
      *(uint4*)&Bl[r * 64 + sl] = *(const uint4*)&Wlo[(size_t)(col0 + r) * 256 + kc + o * 8];
    }
    __syncthreads();
#pragma unroll
    for (int ks = 0; ks < 2; ++ks) {
      short8 ah[2], al[2], bh[4], bl[4];
#pragma unroll
      for (int mi = 0; mi < 2; ++mi) {
        int r = wm * 32 + mi * 16 + lc;
        int sl = (((ks * 4 + lg) ^ (r & 7))) * 8;
        ah[mi] = *(short8*)&Ah[r * 64 + sl];
        al[mi] = *(short8*)&Al[r * 64 + sl];
      }
#pragma unroll
      for (int ni = 0; ni < 4; ++ni) {
        int r = wn * 64 + ni * 16 + lc;
        int sl = (((ks * 4 + lg) ^ (r & 7))) * 8;
        bh[ni] = *(short8*)&Bh[r * 64 + sl];
        bl[ni] = *(short8*)&Bl[r * 64 + sl];
      }
#pragma unroll
      for (int mi = 0; mi < 2; ++mi)
#pragma unroll
        for (int ni = 0; ni < 4; ++ni) {
          acc[mi][ni] = __builtin_amdgcn_mfma_f32_16x16x32_bf16(ah[mi], bh[ni], acc[mi][ni], 0, 0, 0);
          acc[mi][ni] = __builtin_amdgcn_mfma_f32_16x16x32_bf16(ah[mi], bl[ni], acc[mi][ni], 0, 0, 0);
          acc[mi][ni] = __builtin_amdgcn_mfma_f32_16x16x32_bf16(al[mi], bh[ni], acc[mi][ni], 0, 0, 0);
        }
    }
  }

#pragma unroll
  for (int mi = 0; mi < 2; ++mi) {
    int rbase = row0 + wm * 32 + mi * 16 + lg * 4;
#pragma unroll
    for (int ni = 0; ni < 4; ++ni) {
      int col = col0 + wn * 64 + ni * 16 + lc;
#pragma unroll
      for (int j = 0; j < 4; ++j) {
        int row = rbase + j;
        int b = row / NTOK, n = row % NTOK;
        float vv = acc[mi][ni][j];
        if (col < 256) {
          int head = col >> 5, ch = col & 31;
          qb[(((size_t)b * 8 + head) * NTOK + n) * 32 + ch] = vv;
        } else if (col < 512) {
          int o = col - 256; int head = o >> 5, ch = o & 31;
          size_t idx = (((size_t)b * 8 + head) * NTOK + n) * 32 + ch;
          unsigned short h = f2bf(vv);
          khi[idx] = h;
          klo[idx] = f2bf(vv - bf2f(h));
        } else if (col < 768) {
          int o = col - 512; int head = o >> 5, ch = o & 31;
          vT[(((size_t)b * 8 + head) * 32 + ch) * NTOK + n] = f2bf(vv);
        } else {
          int c = col - 768;
          float rv = fmaxf(vv, 0.f);
          resb[((size_t)b * 256 + c) * NTOK + n] = rv;
          if (c >= 64) {
            int g = (c >> 6) - 1, ic = c & 63;
            resT[(((size_t)b * 3 + g) * NTOK + n) * 64 + ic] = f2bf(rv);
          }
        }
      }
    }
  }
}

// ---------------------------------------------------------------------------
// K1b: constrained conv weights -> bf16
// ---------------------------------------------------------------------------
__global__ void k_wprep(const float* __restrict__ k3, const float* __restrict__ k5,
                        const float* __restrict__ k7, unsigned short* __restrict__ wT) {
  int idx = blockIdx.x * 512 + threadIdx.x;
  if (idx >= 83 * 4096) return;
  const float* src; int K, tloc;
  if (idx < 9 * 4096)       { K = 3; src = k3; tloc = idx >> 12; }
  else if (idx < 34 * 4096) { K = 5; src = k5; tloc = (idx - 9 * 4096) >> 12; }
  else                      { K = 7; src = k7; tloc = (idx - 34 * 4096) >> 12; }
  int r = idx & 4095, oc = r >> 6, ic = r & 63;
  int K2 = K * K, ctr = K2 / 2;
  float v = (tloc == ctr) ? -1.f
          : src[((size_t)oc * 64 + ic) * (K2 - 1) + (tloc < ctr ? tloc : tloc - 1)];
  wT[idx] = f2bf(v);
}

// ---------------------------------------------------------------------------
// K2: MFMA flash attention v2.
// QBLK=64 (4 waves), grid 36x32=1152 blocks. Async reg-prefetch of next K/V
// tile (T14), defer-max rescale (T13), setprio around MFMA (T5).
// ---------------------------------------------------------------------------
__global__ __launch_bounds__(256, 4) void k_attn_mfma(
    const float* __restrict__ qb, const unsigned short* __restrict__ khi,
    const unsigned short* __restrict__ klo, const unsigned short* __restrict__ vT,
    float* __restrict__ accb) {
  const int bh = blockIdx.y;
  const int r0 = blockIdx.x * 64;
  const int tid = threadIdx.x;
  const int w = tid >> 6;
  const int lane = tid & 63;
  const int lg = lane >> 4;
  const int lc = lane & 15;

  __shared__ __align__(16) unsigned short ks_hi[64][40];
  __shared__ __align__(16) unsigned short ks_lo[64][40];
  __shared__ __align__(16) unsigned short vs[32][72];
  __shared__ __align__(16) unsigned short ps[4][16][72];

  const float scale = 0.17677669529663688f;

  const float* qp = qb + (((size_t)bh * NTOK + r0 + w * 16 + lc) * 32 + lg * 8);
  float qf[8];
  *(float4*)&qf[0] = *(const float4*)qp;
  *(float4*)&qf[4] = *(const float4*)(qp + 4);
  short8 qh, ql;
#pragma unroll
  for (int i = 0; i < 8; ++i) {
    float v = qf[i] * scale;
    unsigned short h = f2bf(v);
    qh[i] = (short)h;
    ql[i] = (short)f2bf(v - bf2f(h));
  }

  float m_r[4], l_r[4];
#pragma unroll
  for (int j = 0; j < 4; ++j) { m_r[j] = -3.0e38f; l_r[j] = 0.f; }
  f32x4 o0 = {0.f, 0.f, 0.f, 0.f};
  f32x4 o1 = {0.f, 0.f, 0.f, 0.f};

  // staging decomposition for 256 threads
  const int srow = tid >> 2, so4 = (tid & 3) * 8;    // K: 64 rows x 32 ch
  const int vrow = tid >> 3, vp = (tid & 7) * 8;     // V: 32 rows x 64 kv

  const unsigned short* kh_src = khi + ((size_t)bh * NTOK + srow) * 32 + so4;
  const unsigned short* kl_src = klo + ((size_t)bh * NTOK + srow) * 32 + so4;
  const unsigned short* v_src  = vT  + ((size_t)bh * 32 + vrow) * NTOK + vp;

  // prefetch tile 0
  uint4 pk_h = *(const uint4*)kh_src;
  uint4 pk_l = *(const uint4*)kl_src;
  uint4 pv   = *(const uint4*)v_src;

  for (int kt = 0; kt < 36; ++kt) {
    __syncthreads();   // previous tile's LDS consumers done
    *(uint4*)&ks_hi[srow][so4] = pk_h;
    *(uint4*)&ks_lo[srow][so4] = pk_l;
    *(uint4*)&vs[vrow][vp] = pv;
    __syncthreads();

    // issue next tile's loads now; consumed at next loop-top (latency hidden)
    if (kt < 35) {
      int off = (kt + 1) * 64;
      pk_h = *(const uint4*)(kh_src + (size_t)off * 32);
      pk_l = *(const uint4*)(kl_src + (size_t)off * 32);
      pv   = *(const uint4*)(v_src + off);
    }

    // ---- S = Q K^T
    f32x4 s[4];
    __builtin_amdgcn_s_setprio(1);
#pragma unroll
    for (int nt = 0; nt < 4; ++nt) {
      short8 kh = *(short8*)&ks_hi[lc + 16 * nt][lg * 8];
      short8 kl = *(short8*)&ks_lo[lc + 16 * nt][lg * 8];
      f32x4 a = {0.f, 0.f, 0.f, 0.f};
      a = __builtin_amdgcn_mfma_f32_16x16x32_bf16(qh, kh, a, 0, 0, 0);
      a = __builtin_amdgcn_mfma_f32_16x16x32_bf16(qh, kl, a, 0, 0, 0);
      a = __builtin_amdgcn_mfma_f32_16x16x32_bf16(ql, kh, a, 0, 0, 0);
      s[nt] = a;
    }
    __builtin_amdgcn_s_setprio(0);

    // ---- online softmax with defer-max (THR=8)
    float mt[4];
#pragma unroll
    for (int j = 0; j < 4; ++j) {
      float m0 = fmaxf(fmaxf(s[0][j], s[1][j]), fmaxf(s[2][j], s[3][j]));
#pragma unroll
      for (int msk = 1; msk < 16; msk <<= 1) m0 = fmaxf(m0, __shfl_xor(m0, msk, 64));
      mt[j] = m0;
    }
    bool need = (mt[0] > m_r[0] + 8.f) | (mt[1] > m_r[1] + 8.f) |
                (mt[2] > m_r[2] + 8.f) | (mt[3] > m_r[3] + 8.f);
    if (__any(need)) {
#pragma unroll
      for (int j = 0; j < 4; ++j) {
        float mn = fmaxf(m_r[j], mt[j]);
        float corr = __expf(m_r[j] - mn);
        m_r[j] = mn;
        l_r[j] *= corr;
        o0[j] *= corr;
        o1[j] *= corr;
      }
    }
#pragma unroll
    for (int j = 0; j < 4; ++j) {
      float ls = 0.f;
#pragma unroll
      for (int nt = 0; nt < 4; ++nt) {
        float p = __expf(s[nt][j] - m_r[j]);
        s[nt][j] = p;
        ls += p;
      }
#pragma unroll
      for (int msk = 1; msk < 16; msk <<= 1) ls += __shfl_xor(ls, msk, 64);
      l_r[j] += ls;
    }

    // ---- P -> bf16 -> per-wave LDS (D-layout write, A-layout read)
#pragma unroll
    for (int nt = 0; nt < 4; ++nt)
#pragma unroll
      for (int j = 0; j < 4; ++j)
        ps[w][lg * 4 + j][nt * 16 + lc] = f2bf(s[nt][j]);

    __builtin_amdgcn_sched_barrier(0);
    asm volatile("s_waitcnt lgkmcnt(0)" ::: "memory");
    __builtin_amdgcn_sched_barrier(0);

    // ---- O += P V
    __builtin_amdgcn_s_setprio(1);
#pragma unroll
    for (int h2 = 0; h2 < 2; ++h2) {
      short8 pa = *(short8*)&ps[w][lc][h2 * 32 + lg * 8];
      short8 v0 = *(short8*)&vs[lc][h2 * 32 + lg * 8];
      short8 v1 = *(short8*)&vs[lc + 16][h2 * 32 + lg * 8];
      o0 = __builtin_amdgcn_mfma_f32_16x16x32_bf16(pa, v0, o0, 0, 0, 0);
      o1 = __builtin_amdgcn_mfma_f32_16x16x32_bf16(pa, v1, o1, 0, 0, 0);
    }
    __builtin_amdgcn_s_setprio(0);
  }

  float* op = accb + ((size_t)bh * NTOK + r0 + w * 16) * 32;
#pragma unroll
  for (int j = 0; j < 4; ++j) {
    float inv = 1.f / l_r[j];
    int r = lg * 4 + j;
    op[r * 32 + lc] = o0[j] * inv;
    op[r * 32 + lc + 16] = o1[j] * inv;
  }
}

// ---------------------------------------------------------------------------
// K3: avg-pool per (b, channel)
// ---------------------------------------------------------------------------
template <int S>
__global__ void k_pool(const float* __restrict__ resb, float* __restrict__ pooled) {
  constexpr int G = (S == 1) ? 0 : (S == 2) ? 1 : (S == 3) ? 2 : 3;
  constexpr int WSZ = 48 / S;
  constexpr int NPX = WSZ * WSZ;
  int bi = blockIdx.x;
  int b = bi >> 6, cc = bi & 63;
  int c = G * 64 + cc;
  int lane = threadIdx.x;
  const float* src = resb + ((size_t)b * 256 + c) * NTOK;
  const float inv = 1.f / NPX;
  for (int w = 0; w < S * S; ++w) {
    int wy = w / S, wx = w % S;
    float sum = 0.f;
    for (int idx = lane; idx < NPX; idx += 64) {
      int yy = wy * WSZ + idx / WSZ;
      int xx = wx * WSZ + idx % WSZ;
      sum += src[yy * 48 + xx];
    }
#pragma unroll
    for (int msk = 1; msk < 64; msk <<= 1) sum += __shfl_xor(sum, msk, 64);
    if (lane == 0) pooled[((size_t)b * 256 + c) * 36 + w] = sum * inv;
  }
}

// ---------------------------------------------------------------------------
// K4: implicit-GEMM MFMA conv (unchanged)
// ---------------------------------------------------------------------------
template <int K>
__device__ __forceinline__ void conv_core(
    const unsigned short* __restrict__ plane,
    const unsigned short* __restrict__ wTg,
    float* __restrict__ outg,
    unsigned short* lds, int r0, int tid) {
  constexpr int P = K / 2, NR = 2 + 2 * P;
  uint4 zz = {0, 0, 0, 0};
  for (int i = tid; i < 8 * 56 * 8; i += 512) ((uint4*)lds)[i] = zz;
  __syncthreads();
  for (int idx = tid; idx < NR * 384; idx += 512) {
    int i = idx / 384, rem = idx % 384;
    int gx = rem >> 3, o = rem & 7;
    int gy = r0 - P + i;
    if (gy >= 0 && gy < 48) {
      uint4 v = *(const uint4*)(plane + ((size_t)(gy * 48 + gx)) * 64 + o * 8);
      int slot = gx + P;
      *(uint4*)(lds + ((size_t)i * 56 + slot) * 64 + ((o ^ (slot & 7)) * 8)) = v;
    }
  }
  __syncthreads();

  const int w = tid >> 6, lane = tid & 63, lg = lane >> 4, lc = lane & 15;
  const int oc0 = (w >> 1) * 16, ry = w & 1;
  f32x4 acc[3];
  acc[0] = acc[1] = acc[2] = (f32x4){0.f, 0.f, 0.f, 0.f};

  for (int ky = 0; ky < K; ++ky) {
    const unsigned short* rowb = lds + (size_t)(ry + ky) * 56 * 64;
#pragma unroll
    for (int kx = 0; kx < K; ++kx) {
      const int tap = ky * K + kx;
#pragma unroll
      for (int c = 0; c < 2; ++c) {
        short8 aw = *(const short8*)(wTg + (size_t)tap * 4096 + (oc0 + lc) * 64 +
                                     c * 32 + lg * 8);
#pragma unroll
        for (int u = 0; u < 3; ++u) {
          int slot = u * 16 + lc + kx;
          short8 bv = *(const short8*)(rowb + slot * 64 + (((c * 4 + lg) ^ (slot & 7)) * 8));
          acc[u] = __builtin_amdgcn_mfma_f32_16x16x32_bf16(aw, bv, acc[u], 0, 0, 0);
        }
      }
    }
  }
#pragma unroll
  for (int u = 0; u < 3; ++u)
#pragma unroll
    for (int j = 0; j < 4; ++j)
      outg[(size_t)(oc0 + lg * 4 + j) * NTOK + (r0 + ry) * 48 + u * 16 + lc] = acc[u][j];
}

__global__ __launch_bounds__(512, 2) void k_conv_mfma(
    const unsigned short* __restrict__ resT, const unsigned short* __restrict__ wT,
    float* __restrict__ convb) {
  __shared__ __align__(16) unsigned short lds[8 * 56 * 64];
  int bid = blockIdx.x;
  int g = bid % 3, sub = bid / 3;
  int b = sub / 24, r0 = (sub % 24) * 2;
  const unsigned short* plane = resT + (((size_t)b * 3 + g) * NTOK) * 64;
  float* outg = convb + ((size_t)b * 192 + g * 64) * NTOK;
  int tid = threadIdx.x;
  if (g == 0)      conv_core<3>(plane, wT,             outg, lds, r0, tid);
  else if (g == 1) conv_core<5>(plane, wT + 9 * 4096,  outg, lds, r0, tid);
  else             conv_core<7>(plane, wT + 34 * 4096, outg, lds, r0, tid);
}

// ---------------------------------------------------------------------------
// K5: combine -> pre as bf16 hi/lo
// ---------------------------------------------------------------------------
__global__ void k_combine(
    const float* __restrict__ qb, const float* __restrict__ accb,
    const float* __restrict__ resb, const float* __restrict__ convb,
    const float* __restrict__ pooled, unsigned short* __restrict__ preh,
    unsigned short* __restrict__ prel) {
  int nt = blockIdx.x;
  int head = blockIdx.y;
  int b = blockIdx.z;
  int tid = threadIdx.x;
  int n = nt * 8 + (tid >> 5);
  int ch = tid & 31;
  int c = head * 32 + ch;
  int g = c >> 6;
  const int sArr[4] = {1, 2, 3, 6};
  int s = sArr[g];

  size_t qidx = (((size_t)b * 8 + head) * NTOK + n) * 32 + ch;
  float qv = qb[qidx];
  float av = accb[qidx];
  float cvv = (g == 0) ? resb[((size_t)b * 256 + c) * NTOK + n]
                       : convb[((size_t)b * 192 + (c - 64)) * NTOK + n];
  const float* pl = pooled + ((size_t)b * 256 + c) * 36;
  float lp;
  if (s == 1) {
    lp = pl[0];
  } else {
    int yy = n / 48, xx = n % 48;
    float fs = (float)(s - 1) / 47.0f;
    float ry = yy * fs, rx = xx * fs;
    int y0 = (int)ry, x0 = (int)rx;
    int y1 = min(y0 + 1, s - 1), x1 = min(x0 + 1, s - 1);
    float wy = ry - (float)y0, wx = rx - (float)x0;
    float v00 = pl[y0 * s + x0], v01 = pl[y0 * s + x1];
    float v10 = pl[y1 * s + x0], v11 = pl[y1 * s + x1];
    lp = v00 * (1 - wy) * (1 - wx) + v01 * (1 - wy) * wx +
         v10 * wy * (1 - wx) + v11 * wy * wx;
  }
  lp = fmaxf(lp, 0.f);
  float val = av + qv * cvv + lp;
  unsigned short h = f2bf(val);
  size_t oidx = ((size_t)b * NTOK + n) * 256 + c;
  preh[oidx] = h;
  prel[oidx] = f2bf(val - bf2f(h));
}

// ---------------------------------------------------------------------------
// K6: MFMA split-bf16 projection GEMM
// ---------------------------------------------------------------------------
__global__ __launch_bounds__(512, 2) void k_gemm_proj_mfma(
    const unsigned short* __restrict__ preh, const unsigned short* __restrict__ prel,
    const unsigned short* __restrict__ pwhi, const unsigned short* __restrict__ pwlo,
    const float* __restrict__ bproj, float* __restrict__ outp) {
  __shared__ __align__(16) unsigned short Ah[128 * 64];
  __shared__ __align__(16) unsigned short Al[128 * 64];
  __shared__ __align__(16) unsigned short Bh[128 * 64];
  __shared__ __align__(16) unsigned short Bl[128 * 64];
  const int tid = threadIdx.x;
  const int row0 = blockIdx.x * 128;
  const int col0 = blockIdx.y * 128;
  const int w = tid >> 6, lane = tid & 63, lg = lane >> 4, lc = lane & 15;
  const int wm = w >> 1, wn = w & 1;

  f32x4 acc[2][4];
#pragma unroll
  for (int i = 0; i < 2; ++i)
#pragma unroll
    for (int j = 0; j < 4; ++j) acc[i][j] = (f32x4){0.f, 0.f, 0.f, 0.f};

  for (int kc = 0; kc < 256; kc += 64) {
    __syncthreads();
#pragma unroll
    for (int l = 0; l < 2; ++l) {
      int idx = tid + l * 512;
      int r = idx >> 3, o = idx & 7;
      int sl = ((o ^ (r & 7))) * 8;
      *(uint4*)&Ah[r * 64 + sl] = *(const uint4*)&preh[(size_t)(row0 + r) * 256 + kc + o * 8];
      *(uint4*)&Al[r * 64 + sl] = *(const uint4*)&prel[(size_t)(row0 + r) * 256 + kc + o * 8];
      *(uint4*)&Bh[r * 64 + sl] = *(const uint4*)&pwhi[(size_t)(col0 + r) * 256 + kc + o * 8];
      *(uint4*)&Bl[r * 64 + sl] = *(const uint4*)&pwlo[(size_t)(col0 + r) * 256 + kc + o * 8];
    }
    __syncthreads();
#pragma unroll
    for (int ks = 0; ks < 2; ++ks) {
      short8 ah[2], al[2], bh[4], bl[4];
#pragma unroll
      for (int mi = 0; mi < 2; ++mi) {
        int r = wm * 32 + mi * 16 + lc;
        int sl = (((ks * 4 + lg) ^ (r & 7))) * 8;
        ah[mi] = *(short8*)&Ah[r * 64 + sl];
        al[mi] = *(short8*)&Al[r * 64 + sl];
      }
#pragma unroll
      for (int ni = 0; ni < 4; ++ni) {
        int r = wn * 64 + ni * 16 + lc;
        int sl = (((ks * 4 + lg) ^ (r & 7))) * 8;
        bh[ni] = *(short8*)&Bh[r * 64 + sl];
        bl[ni] = *(short8*)&Bl[r * 64 + sl];
      }
#pragma unroll
      for (int mi = 0; mi < 2; ++mi)
#pragma unroll
        for (int ni = 0; ni < 4; ++ni) {
          acc[mi][ni] = __builtin_amdgcn_mfma_f32_16x16x32_bf16(ah[mi], bh[ni], acc[mi][ni], 0, 0, 0);
          acc[mi][ni] = __builtin_amdgcn_mfma_f32_16x16x32_bf16(ah[mi], bl[ni], acc[mi][ni], 0, 0, 0);
          acc[mi][ni] = __builtin_amdgcn_mfma_f32_16x16x32_bf16(al[mi], bh[ni], acc[mi][ni], 0, 0, 0);
        }
    }
  }

#pragma unroll
  for (int mi = 0; mi < 2; ++mi) {
    int rbase = row0 + wm * 32 + mi * 16 + lg * 4;
#pragma unroll
    for (int ni = 0; ni < 4; ++ni) {
      int col = col0 + wn * 64 + ni * 16 + lc;
#pragma unroll
      for (int j = 0; j < 4; ++j)
        outp[(size_t)(rbase + j) * 256 + col] = acc[mi][ni][j] + bproj[col];
    }
  }
}

// ---------------------------------------------------------------------------
extern "C" void kernel_launch(void* const* d_in, const int* in_sizes, int n_in,
                              void* d_out, int out_size, void* d_ws, size_t ws_size,
                              hipStream_t stream) {
  const float* x     = (const float*)d_in[0];
  const float* wq    = (const float*)d_in[3];
  const float* wkv   = (const float*)d_in[4];
  const float* wres  = (const float*)d_in[5];
  const float* wproj = (const float*)d_in[6];
  const float* bproj = (const float*)d_in[7];
  const float* kern3 = (const float*)d_in[8];
  const float* kern5 = (const float*)d_in[9];
  const float* kern7 = (const float*)d_in[10];

  const size_t SZ = (size_t)4 * 8 * NTOK * 32;   // 2,359,296
  float* wsf  = (float*)d_ws;
  float* qb   = wsf;                              // [0, SZ)
  float* resb = wsf + SZ;                         // [SZ, 2SZ)
  float* accb = wsf + 2 * SZ;                     // [2SZ, 3SZ)
  unsigned short* xhi = (unsigned short*)(wsf + 2 * SZ);
  unsigned short* xlo = (unsigned short*)(wsf + 2 * SZ + SZ / 2);
  unsigned short* khi = (unsigned short*)(wsf + 3 * SZ);
  unsigned short* klo = (unsigned short*)(wsf + 3 * SZ + SZ / 2);
  unsigned short* vT  = (unsigned short*)(wsf + 4 * SZ);
  unsigned short* resT = (unsigned short*)(wsf + 4 * SZ + SZ / 2);
  unsigned short* wT   = (unsigned short*)(wsf + 4 * SZ + SZ / 2 + 884736);
  unsigned short* Whi = (unsigned short*)(wsf + 4 * SZ + SZ / 2 + 884736 + 169984);
  unsigned short* Wlo = Whi + 262144;
  float* convb  = wsf + 3 * SZ;
  float* pooled = wsf + 4 * SZ;
  unsigned short* pwhi = (unsigned short*)(wsf + 4 * SZ + 40960);
  unsigned short* pwlo = pwhi + 65536;
  unsigned short* preh = (unsigned short*)(wsf + 4 * SZ + SZ / 2);
  unsigned short* prel = (unsigned short*)(wsf + 5 * SZ);
  float* outp = (float*)d_out;

  k_prep_x<<<dim3(2304), 256, 0, stream>>>(x, xhi, xlo);
  k_prep_w<<<dim3(256), 256, 0, stream>>>(wq, wkv, wres, Whi, Wlo);
  k_wprep<<<dim3(664), 512, 0, stream>>>(kern3, kern5, kern7, wT);
  k_gemm_qkvres_mfma<<<dim3(72, 8), 512, 0, stream>>>(xhi, xlo, Whi, Wlo, qb, khi,
                                                      klo, vT, resb, resT);
  k_attn_mfma<<<dim3(36, 32), 256, 0, stream>>>(qb, khi, klo, vT, accb);
  k_pool<1><<<dim3(256), 64, 0, stream>>>(resb, pooled);
  k_pool<2><<<dim3(256), 64, 0, stream>>>(resb, pooled);
  k_pool<3><<<dim3(256), 64, 0, stream>>>(resb, pooled);
  k_pool<6><<<dim3(256), 64, 0, stream>>>(resb, pooled);
  k_prep_wproj<<<dim3(64), 256, 0, stream>>>(wproj, pwhi, pwlo);
  k_conv_mfma<<<dim3(288), 512, 0, stream>>>(resT, wT, convb);
  k_combine<<<dim3(288, 8, 4), 256, 0, stream>>>(qb, accb, resb, convb, pooled,
                                                 preh, prel);
  k_gemm_proj_mfma<<<dim3(72, 2), 512, 0, stream>>>(preh, prel, pwhi, pwlo, bproj, outp);
}

// Round 6
// 283.228 us; speedup vs baseline: 6.8484x; 1.0862x over previous
//
#include <hip/hip_runtime.h>
#include <math.h>

#define NTOK 2304   // N = 48*48
#define DIMC 256

typedef __attribute__((ext_vector_type(8))) short short8;
typedef __attribute__((ext_vector_type(4))) float f32x4;

__device__ __forceinline__ unsigned short f2bf(float f) {
  unsigned u = __float_as_uint(f);
  u += 0x7fffu + ((u >> 16) & 1u);
  return (unsigned short)(u >> 16);
}
__device__ __forceinline__ float bf2f(unsigned short h) {
  return __uint_as_float(((unsigned)h) << 16);
}
__device__ __forceinline__ unsigned pack2(float a, float b) {
  return (unsigned)f2bf(a) | ((unsigned)f2bf(b) << 16);
}

// ---------------------------------------------------------------------------
// P1: split x -> bf16 hi/lo
// ---------------------------------------------------------------------------
__global__ __launch_bounds__(256) void k_prep_x(
    const float* __restrict__ x, unsigned short* __restrict__ xhi,
    unsigned short* __restrict__ xlo) {
  int i = blockIdx.x * 256 + threadIdx.x;
  float4 v = ((const float4*)x)[i];
  unsigned short h0 = f2bf(v.x), h1 = f2bf(v.y), h2 = f2bf(v.z), h3 = f2bf(v.w);
  unsigned short l0 = f2bf(v.x - bf2f(h0)), l1 = f2bf(v.y - bf2f(h1));
  unsigned short l2 = f2bf(v.z - bf2f(h2)), l3 = f2bf(v.w - bf2f(h3));
  uint2 hp, lp;
  hp.x = (unsigned)h0 | ((unsigned)h1 << 16);
  hp.y = (unsigned)h2 | ((unsigned)h3 << 16);
  lp.x = (unsigned)l0 | ((unsigned)l1 << 16);
  lp.y = (unsigned)l2 | ((unsigned)l3 << 16);
  ((uint2*)xhi)[i] = hp;
  ((uint2*)xlo)[i] = lp;
}

// ---------------------------------------------------------------------------
// P2: split fused W = [wq;wkv;wres] -> hi/lo
// ---------------------------------------------------------------------------
__global__ __launch_bounds__(256) void k_prep_w(
    const float* __restrict__ wq, const float* __restrict__ wkv,
    const float* __restrict__ wres, unsigned short* __restrict__ Whi,
    unsigned short* __restrict__ Wlo) {
  int idx = blockIdx.x * 256 + threadIdx.x;
  int row = idx >> 6, q4 = idx & 63;
  const float* src;
  if (row < 256)      src = wq + (size_t)row * 256;
  else if (row < 768) src = wkv + (size_t)(row - 256) * 256;
  else                src = wres + (size_t)(row - 768) * 256;
  float4 v = *(const float4*)(src + q4 * 4);
  unsigned short h0 = f2bf(v.x), h1 = f2bf(v.y), h2 = f2bf(v.z), h3 = f2bf(v.w);
  unsigned short l0 = f2bf(v.x - bf2f(h0)), l1 = f2bf(v.y - bf2f(h1));
  unsigned short l2 = f2bf(v.z - bf2f(h2)), l3 = f2bf(v.w - bf2f(h3));
  uint2 hp, lp;
  hp.x = (unsigned)h0 | ((unsigned)h1 << 16);
  hp.y = (unsigned)h2 | ((unsigned)h3 << 16);
  lp.x = (unsigned)l0 | ((unsigned)l1 << 16);
  lp.y = (unsigned)l2 | ((unsigned)l3 << 16);
  ((uint2*)Whi)[idx] = hp;
  ((uint2*)Wlo)[idx] = lp;
}

// ---------------------------------------------------------------------------
// P3: split wproj -> hi/lo
// ---------------------------------------------------------------------------
__global__ __launch_bounds__(256) void k_prep_wproj(
    const float* __restrict__ wproj, unsigned short* __restrict__ pwhi,
    unsigned short* __restrict__ pwlo) {
  int idx = blockIdx.x * 256 + threadIdx.x;
  float4 v = ((const float4*)wproj)[idx];
  unsigned short h0 = f2bf(v.x), h1 = f2bf(v.y), h2 = f2bf(v.z), h3 = f2bf(v.w);
  unsigned short l0 = f2bf(v.x - bf2f(h0)), l1 = f2bf(v.y - bf2f(h1));
  unsigned short l2 = f2bf(v.z - bf2f(h2)), l3 = f2bf(v.w - bf2f(h3));
  uint2 hp, lp;
  hp.x = (unsigned)h0 | ((unsigned)h1 << 16);
  hp.y = (unsigned)h2 | ((unsigned)h3 << 16);
  lp.x = (unsigned)l0 | ((unsigned)l1 << 16);
  lp.y = (unsigned)l2 | ((unsigned)l3 << 16);
  ((uint2*)pwhi)[idx] = hp;
  ((uint2*)pwlo)[idx] = lp;
}

// ---------------------------------------------------------------------------
// K1: MFMA split-bf16 fused GEMM (unchanged)
// ---------------------------------------------------------------------------
__global__ __launch_bounds__(512, 2) void k_gemm_qkvres_mfma(
    const unsigned short* __restrict__ xhi, const unsigned short* __restrict__ xlo,
    const unsigned short* __restrict__ Whi, const unsigned short* __restrict__ Wlo,
    float* __restrict__ qb, unsigned short* __restrict__ khi,
    unsigned short* __restrict__ klo, unsigned short* __restrict__ vT,
    float* __restrict__ resb, unsigned short* __restrict__ resT) {
  __shared__ __align__(16) unsigned short Ah[128 * 64];
  __shared__ __align__(16) unsigned short Al[128 * 64];
  __shared__ __align__(16) unsigned short Bh[128 * 64];
  __shared__ __align__(16) unsigned short Bl[128 * 64];
  const int tid = threadIdx.x;
  const int row0 = blockIdx.x * 128;
  const int col0 = blockIdx.y * 128;
  const int w = tid >> 6, lane = tid & 63, lg = lane >> 4, lc = lane & 15;
  const int wm = w >> 1, wn = w & 1;

  f32x4 acc[2][4];
#pragma unroll
  for (int i = 0; i < 2; ++i)
#pragma unroll
    for (int j = 0; j < 4; ++j) acc[i][j] = (f32x4){0.f, 0.f, 0.f, 0.f};

  for (int kc = 0; kc < 256; kc += 64) {
    __syncthreads();
#pragma unroll
    for (int l = 0; l < 2; ++l) {
      int idx = tid + l * 512;
      int r = idx >> 3, o = idx & 7;
      int sl = ((o ^ (r & 7))) * 8;
      *(uint4*)&Ah[r * 64 + sl] = *(const uint4*)&xhi[(size_t)(row0 + r) * 256 + kc + o * 8];
      *(uint4*)&Al[r * 64 + sl] = *(const uint4*)&xlo[(size_t)(row0 + r) * 256 + kc + o * 8];
      *(uint4*)&Bh[r * 64 + sl] = *(const uint4*)&Whi[(size_t)(col0 + r) * 256 + kc + o * 8];
      *(uint4*)&Bl[r * 64 + sl] = *(const uint4*)&Wlo[(size_t)(col0 + r) * 256 + kc + o * 8];
    }
    __syncthreads();
#pragma unroll
    for (int ks = 0; ks < 2; ++ks) {
      short8 ah[2], al[2], bh[4], bl[4];
#pragma unroll
      for (int mi = 0; mi < 2; ++mi) {
        int r = wm * 32 + mi * 16 + lc;
        int sl = (((ks * 4 + lg) ^ (r & 7))) * 8;
        ah[mi] = *(short8*)&Ah[r * 64 + sl];
        al[mi] = *(short8*)&Al[r * 64 + sl];
      }
#pragma unroll
      for (int ni = 0; ni < 4; ++ni) {
        int r = wn * 64 + ni * 16 + lc;
        int sl = (((ks * 4 + lg) ^ (r & 7))) * 8;
        bh[ni] = *(short8*)&Bh[r * 64 + sl];
        bl[ni] = *(short8*)&Bl[r * 64 + sl];
      }
#pragma unroll
      for (int mi = 0; mi < 2; ++mi)
#pragma unroll
        for (int ni = 0; ni < 4; ++ni) {
          acc[mi][ni] = __builtin_amdgcn_mfma_f32_16x16x32_bf16(ah[mi], bh[ni], acc[mi][ni], 0, 0, 0);
          acc[mi][ni] = __builtin_amdgcn_mfma_f32_16x16x32_bf16(ah[mi], bl[ni], acc[mi][ni], 0, 0, 0);
          acc[mi][ni] = __builtin_amdgcn_mfma_f32_16x16x32_bf16(al[mi], bh[ni], acc[mi][ni], 0, 0, 0);
        }
    }
  }

#pragma unroll
  for (int mi = 0; mi < 2; ++mi) {
    int rbase = row0 + wm * 32 + mi * 16 + lg * 4;
#pragma unroll
    for (int ni = 0; ni < 4; ++ni) {
      int col = col0 + wn * 64 + ni * 16 + lc;
#pragma unroll
      for (int j = 0; j < 4; ++j) {
        int row = rbase + j;
        int b = row / NTOK, n = row % NTOK;
        float vv = acc[mi][ni][j];
        if (col < 256) {
          int head = col >> 5, ch = col & 31;
          qb[(((size_t)b * 8 + head) * NTOK + n) * 32 + ch] = vv;
        } else if (col < 512) {
          int o = col - 256; int head = o >> 5, ch = o & 31;
          size_t idx = (((size_t)b * 8 + head) * NTOK + n) * 32 + ch;
          unsigned short h = f2bf(vv);
          khi[idx] = h;
          klo[idx] = f2bf(vv - bf2f(h));
        } else if (col < 768) {
          int o = col - 512; int head = o >> 5, ch = o & 31;
          vT[(((size_t)b * 8 + head) * 32 + ch) * NTOK + n] = f2bf(vv);
        } else {
          int c = col - 768;
          float rv = fmaxf(vv, 0.f);
          resb[((size_t)b * 256 + c) * NTOK + n] = rv;
          if (c >= 64) {
            int g = (c >> 6) - 1, ic = c & 63;
            resT[(((size_t)b * 3 + g) * NTOK + n) * 64 + ic] = f2bf(rv);
          }
        }
      }
    }
  }
}

// ---------------------------------------------------------------------------
// K1b: constrained conv weights -> bf16
// ---------------------------------------------------------------------------
__global__ void k_wprep(const float* __restrict__ k3, const float* __restrict__ k5,
                        const float* __restrict__ k7, unsigned short* __restrict__ wT) {
  int idx = blockIdx.x * 512 + threadIdx.x;
  if (idx >= 83 * 4096) return;
  const float* src; int K, tloc;
  if (idx < 9 * 4096)       { K = 3; src = k3; tloc = idx >> 12; }
  else if (idx < 34 * 4096) { K = 5; src = k5; tloc = (idx - 9 * 4096) >> 12; }
  else                      { K = 7; src = k7; tloc = (idx - 34 * 4096) >> 12; }
  int r = idx & 4095, oc = r >> 6, ic = r & 63;
  int K2 = K * K, ctr = K2 / 2;
  float v = (tloc == ctr) ? -1.f
          : src[((size_t)oc * 64 + ic) * (K2 - 1) + (tloc < ctr ? tloc : tloc - 1)];
  wT[idx] = f2bf(v);
}

// ---------------------------------------------------------------------------
// K2: MFMA flash attention v3 — swapped QK^T (P in-register, q = lane&15),
// KVBLK=128, lane-local softmax + 2 shfl_xor, shuffle-based P->A-frag
// redistribution (no LDS P), reg prefetch of next tile, defer-max.
// ---------------------------------------------------------------------------
__global__ __launch_bounds__(256, 4) void k_attn_mfma(
    const float* __restrict__ qb, const unsigned short* __restrict__ khi,
    const unsigned short* __restrict__ klo, const unsigned short* __restrict__ vT,
    float* __restrict__ accb) {
  const int bh = blockIdx.y;
  const int r0 = blockIdx.x * 64;
  const int tid = threadIdx.x;
  const int w = tid >> 6;
  const int lane = tid & 63;
  const int lg = lane >> 4;      // 0..3
  const int lc = lane & 15;      // 0..15

  __shared__ __align__(16) unsigned short ks_hi[128][40];
  __shared__ __align__(16) unsigned short ks_lo[128][40];
  __shared__ __align__(16) unsigned short vs[32][136];

  const float scale = 0.17677669529663688f;   // 32^-0.5

  // Q fragment (B-side): q-row = lc, ch = lg*8+i. Same regs as before.
  const float* qp = qb + (((size_t)bh * NTOK + r0 + w * 16 + lc) * 32 + lg * 8);
  float qf[8];
  *(float4*)&qf[0] = *(const float4*)qp;
  *(float4*)&qf[4] = *(const float4*)(qp + 4);
  short8 qh, ql;
#pragma unroll
  for (int i = 0; i < 8; ++i) {
    float v = qf[i] * scale;
    unsigned short h = f2bf(v);
    qh[i] = (short)h;
    ql[i] = (short)f2bf(v - bf2f(h));
  }

  float m_r = -3.0e38f, l_r = 0.f;   // per-lane: q-row = lc
  f32x4 o0 = {0.f, 0.f, 0.f, 0.f};   // D: q-row = lg*4+j, ch = lc
  f32x4 o1 = {0.f, 0.f, 0.f, 0.f};   // ch = lc+16

  // staging decomposition (256 threads)
  const int krow = tid >> 1, kseg = (tid & 1) * 16;   // K: 128 rows x 32 ch
  const int vrow = tid >> 3, vseg = (tid & 7) * 16;   // V: 32 ch x 128 kv

  const unsigned short* khs = khi + ((size_t)bh * NTOK + krow) * 32 + kseg;
  const unsigned short* kls = klo + ((size_t)bh * NTOK + krow) * 32 + kseg;
  const unsigned short* vsrc = vT + ((size_t)bh * 32 + vrow) * NTOK + vseg;

  // prefetch tile 0
  uint4 ph0 = *(const uint4*)khs,       ph1 = *(const uint4*)(khs + 8);
  uint4 pl0 = *(const uint4*)kls,       pl1 = *(const uint4*)(kls + 8);
  uint4 pv0 = *(const uint4*)vsrc,      pv1 = *(const uint4*)(vsrc + 8);

  const int srcA = ((lg & 1) * 2) * 16 + lc;   // bpermute source lane (lo half)

  for (int kt = 0; kt < 18; ++kt) {
    __syncthreads();   // previous tile's LDS consumers done
    *(uint4*)&ks_hi[krow][kseg]     = ph0;
    *(uint4*)&ks_hi[krow][kseg + 8] = ph1;
    *(uint4*)&ks_lo[krow][kseg]     = pl0;
    *(uint4*)&ks_lo[krow][kseg + 8] = pl1;
    *(uint4*)&vs[vrow][vseg]        = pv0;
    *(uint4*)&vs[vrow][vseg + 8]    = pv1;
    __syncthreads();

    // issue next tile's loads; consumed at next loop-top (latency hidden)
    if (kt < 17) {
      size_t ko = (size_t)(kt + 1) * 128 * 32;
      int vo = (kt + 1) * 128;
      ph0 = *(const uint4*)(khs + ko);      ph1 = *(const uint4*)(khs + ko + 8);
      pl0 = *(const uint4*)(kls + ko);      pl1 = *(const uint4*)(kls + ko + 8);
      pv0 = *(const uint4*)(vsrc + vo);     pv1 = *(const uint4*)(vsrc + vo + 8);
    }

    // ---- S^T = K Q^T : lane holds S[q=lc][kv = nt*16 + lg*4 + j]
    f32x4 s[8];
    __builtin_amdgcn_s_setprio(1);
#pragma unroll
    for (int nt = 0; nt < 8; ++nt) {
      short8 kh = *(short8*)&ks_hi[nt * 16 + lc][lg * 8];
      short8 kl = *(short8*)&ks_lo[nt * 16 + lc][lg * 8];
      f32x4 a = {0.f, 0.f, 0.f, 0.f};
      a = __builtin_amdgcn_mfma_f32_16x16x32_bf16(kh, qh, a, 0, 0, 0);
      a = __builtin_amdgcn_mfma_f32_16x16x32_bf16(kl, qh, a, 0, 0, 0);
      a = __builtin_amdgcn_mfma_f32_16x16x32_bf16(kh, ql, a, 0, 0, 0);
      s[nt] = a;
    }
    __builtin_amdgcn_s_setprio(0);

    // ---- lane-local row max (32 values) + 2-lane-group reduce
    float mx[8];
#pragma unroll
    for (int nt = 0; nt < 8; ++nt)
      mx[nt] = fmaxf(fmaxf(s[nt][0], s[nt][1]), fmaxf(s[nt][2], s[nt][3]));
    float mt = fmaxf(fmaxf(fmaxf(mx[0], mx[1]), fmaxf(mx[2], mx[3])),
                     fmaxf(fmaxf(mx[4], mx[5]), fmaxf(mx[6], mx[7])));
    mt = fmaxf(mt, __shfl_xor(mt, 16, 64));
    mt = fmaxf(mt, __shfl_xor(mt, 32, 64));

    // ---- defer-max rescale (THR=8)
    if (__any(mt > m_r + 8.f)) {
      float mn = fmaxf(m_r, mt);
      float corr = __expf(m_r - mn);
      m_r = mn;
      l_r *= corr;
#pragma unroll
      for (int j = 0; j < 4; ++j) {
        float cj = __shfl(corr, lg * 4 + j, 64);
        o0[j] *= cj;
        o1[j] *= cj;
      }
    }

    // ---- exp + row sum (lane-local + 2 shfl)
    float ls = 0.f;
#pragma unroll
    for (int nt = 0; nt < 8; ++nt)
#pragma unroll
      for (int j = 0; j < 4; ++j) {
        float p = __expf(s[nt][j] - m_r);
        s[nt][j] = p;
        ls += p;
      }
    ls += __shfl_xor(ls, 16, 64);
    ls += __shfl_xor(ls, 32, 64);
    l_r += ls;

    // ---- pack P to bf16 pairs (kv-contiguous within each nt)
    unsigned W[8][2];
#pragma unroll
    for (int nt = 0; nt < 8; ++nt) {
      W[nt][0] = pack2(s[nt][0], s[nt][1]);
      W[nt][1] = pack2(s[nt][2], s[nt][3]);
    }

    // ---- O += P V : redistribute P to A-frag via shuffles, MFMA with V
    __builtin_amdgcn_s_setprio(1);
#pragma unroll
    for (int h2 = 0; h2 < 4; ++h2) {
      unsigned v0 = (lg & 2) ? W[2 * h2 + 1][0] : W[2 * h2][0];
      unsigned v1 = (lg & 2) ? W[2 * h2 + 1][1] : W[2 * h2][1];
      union { unsigned u[4]; short8 v; } pa;
      pa.u[0] = (unsigned)__shfl((int)v0, srcA, 64);
      pa.u[1] = (unsigned)__shfl((int)v1, srcA, 64);
      pa.u[2] = (unsigned)__shfl((int)v0, srcA + 16, 64);
      pa.u[3] = (unsigned)__shfl((int)v1, srcA + 16, 64);
      short8 vf0 = *(short8*)&vs[lc][h2 * 32 + lg * 8];
      short8 vf1 = *(short8*)&vs[lc + 16][h2 * 32 + lg * 8];
      o0 = __builtin_amdgcn_mfma_f32_16x16x32_bf16(pa.v, vf0, o0, 0, 0, 0);
      o1 = __builtin_amdgcn_mfma_f32_16x16x32_bf16(pa.v, vf1, o1, 0, 0, 0);
    }
    __builtin_amdgcn_s_setprio(0);
  }

  float* op = accb + ((size_t)bh * NTOK + r0 + w * 16) * 32;
#pragma unroll
  for (int j = 0; j < 4; ++j) {
    float lj = __shfl(l_r, lg * 4 + j, 64);
    float inv = 1.f / lj;
    int r = lg * 4 + j;
    op[r * 32 + lc] = o0[j] * inv;
    op[r * 32 + lc + 16] = o1[j] * inv;
  }
}

// ---------------------------------------------------------------------------
// K3: avg-pool per (b, channel)
// ---------------------------------------------------------------------------
template <int S>
__global__ void k_pool(const float* __restrict__ resb, float* __restrict__ pooled) {
  constexpr int G = (S == 1) ? 0 : (S == 2) ? 1 : (S == 3) ? 2 : 3;
  constexpr int WSZ = 48 / S;
  constexpr int NPX = WSZ * WSZ;
  int bi = blockIdx.x;
  int b = bi >> 6, cc = bi & 63;
  int c = G * 64 + cc;
  int lane = threadIdx.x;
  const float* src = resb + ((size_t)b * 256 + c) * NTOK;
  const float inv = 1.f / NPX;
  for (int w = 0; w < S * S; ++w) {
    int wy = w / S, wx = w % S;
    float sum = 0.f;
    for (int idx = lane; idx < NPX; idx += 64) {
      int yy = wy * WSZ + idx / WSZ;
      int xx = wx * WSZ + idx % WSZ;
      sum += src[yy * 48 + xx];
    }
#pragma unroll
    for (int msk = 1; msk < 64; msk <<= 1) sum += __shfl_xor(sum, msk, 64);
    if (lane == 0) pooled[((size_t)b * 256 + c) * 36 + w] = sum * inv;
  }
}

// ---------------------------------------------------------------------------
// K4: implicit-GEMM MFMA conv (unchanged)
// ---------------------------------------------------------------------------
template <int K>
__device__ __forceinline__ void conv_core(
    const unsigned short* __restrict__ plane,
    const unsigned short* __restrict__ wTg,
    float* __restrict__ outg,
    unsigned short* lds, int r0, int tid) {
  constexpr int P = K / 2, NR = 2 + 2 * P;
  uint4 zz = {0, 0, 0, 0};
  for (int i = tid; i < 8 * 56 * 8; i += 512) ((uint4*)lds)[i] = zz;
  __syncthreads();
  for (int idx = tid; idx < NR * 384; idx += 512) {
    int i = idx / 384, rem = idx % 384;
    int gx = rem >> 3, o = rem & 7;
    int gy = r0 - P + i;
    if (gy >= 0 && gy < 48) {
      uint4 v = *(const uint4*)(plane + ((size_t)(gy * 48 + gx)) * 64 + o * 8);
      int slot = gx + P;
      *(uint4*)(lds + ((size_t)i * 56 + slot) * 64 + ((o ^ (slot & 7)) * 8)) = v;
    }
  }
  __syncthreads();

  const int w = tid >> 6, lane = tid & 63, lg = lane >> 4, lc = lane & 15;
  const int oc0 = (w >> 1) * 16, ry = w & 1;
  f32x4 acc[3];
  acc[0] = acc[1] = acc[2] = (f32x4){0.f, 0.f, 0.f, 0.f};

  for (int ky = 0; ky < K; ++ky) {
    const unsigned short* rowb = lds + (size_t)(ry + ky) * 56 * 64;
#pragma unroll
    for (int kx = 0; kx < K; ++kx) {
      const int tap = ky * K + kx;
#pragma unroll
      for (int c = 0; c < 2; ++c) {
        short8 aw = *(const short8*)(wTg + (size_t)tap * 4096 + (oc0 + lc) * 64 +
                                     c * 32 + lg * 8);
#pragma unroll
        for (int u = 0; u < 3; ++u) {
          int slot = u * 16 + lc + kx;
          short8 bv = *(const short8*)(rowb + slot * 64 + (((c * 4 + lg) ^ (slot & 7)) * 8));
          acc[u] = __builtin_amdgcn_mfma_f32_16x16x32_bf16(aw, bv, acc[u], 0, 0, 0);
        }
      }
    }
  }
#pragma unroll
  for (int u = 0; u < 3; ++u)
#pragma unroll
    for (int j = 0; j < 4; ++j)
      outg[(size_t)(oc0 + lg * 4 + j) * NTOK + (r0 + ry) * 48 + u * 16 + lc] = acc[u][j];
}

__global__ __launch_bounds__(512, 2) void k_conv_mfma(
    const unsigned short* __restrict__ resT, const unsigned short* __restrict__ wT,
    float* __restrict__ convb) {
  __shared__ __align__(16) unsigned short lds[8 * 56 * 64];
  int bid = blockIdx.x;
  int g = bid % 3, sub = bid / 3;
  int b = sub / 24, r0 = (sub % 24) * 2;
  const unsigned short* plane = resT + (((size_t)b * 3 + g) * NTOK) * 64;
  float* outg = convb + ((size_t)b * 192 + g * 64) * NTOK;
  int tid = threadIdx.x;
  if (g == 0)      conv_core<3>(plane, wT,             outg, lds, r0, tid);
  else if (g == 1) conv_core<5>(plane, wT + 9 * 4096,  outg, lds, r0, tid);
  else             conv_core<7>(plane, wT + 34 * 4096, outg, lds, r0, tid);
}

// ---------------------------------------------------------------------------
// K5: combine -> pre as bf16 hi/lo
// ---------------------------------------------------------------------------
__global__ void k_combine(
    const float* __restrict__ qb, const float* __restrict__ accb,
    const float* __restrict__ resb, const float* __restrict__ convb,
    const float* __restrict__ pooled, unsigned short* __restrict__ preh,
    unsigned short* __restrict__ prel) {
  int nt = blockIdx.x;
  int head = blockIdx.y;
  int b = blockIdx.z;
  int tid = threadIdx.x;
  int n = nt * 8 + (tid >> 5);
  int ch = tid & 31;
  int c = head * 32 + ch;
  int g = c >> 6;
  const int sArr[4] = {1, 2, 3, 6};
  int s = sArr[g];

  size_t qidx = (((size_t)b * 8 + head) * NTOK + n) * 32 + ch;
  float qv = qb[qidx];
  float av = accb[qidx];
  float cvv = (g == 0) ? resb[((size_t)b * 256 + c) * NTOK + n]
                       : convb[((size_t)b * 192 + (c - 64)) * NTOK + n];
  const float* pl = pooled + ((size_t)b * 256 + c) * 36;
  float lp;
  if (s == 1) {
    lp = pl[0];
  } else {
    int yy = n / 48, xx = n % 48;
    float fs = (float)(s - 1) / 47.0f;
    float ry = yy * fs, rx = xx * fs;
    int y0 = (int)ry, x0 = (int)rx;
    int y1 = min(y0 + 1, s - 1), x1 = min(x0 + 1, s - 1);
    float wy = ry - (float)y0, wx = rx - (float)x0;
    float v00 = pl[y0 * s + x0], v01 = pl[y0 * s + x1];
    float v10 = pl[y1 * s + x0], v11 = pl[y1 * s + x1];
    lp = v00 * (1 - wy) * (1 - wx) + v01 * (1 - wy) * wx +
         v10 * wy * (1 - wx) + v11 * wy * wx;
  }
  lp = fmaxf(lp, 0.f);
  float val = av + qv * cvv + lp;
  unsigned short h = f2bf(val);
  size_t oidx = ((size_t)b * NTOK + n) * 256 + c;
  preh[oidx] = h;
  prel[oidx] = f2bf(val - bf2f(h));
}

// ---------------------------------------------------------------------------
// K6: MFMA split-bf16 projection GEMM (unchanged)
// ---------------------------------------------------------------------------
__global__ __launch_bounds__(512, 2) void k_gemm_proj_mfma(
    const unsigned short* __restrict__ preh, const unsigned short* __restrict__ prel,
    const unsigned short* __restrict__ pwhi, const unsigned short* __restrict__ pwlo,
    const float* __restrict__ bproj, float* __restrict__ outp) {
  __shared__ __align__(16) unsigned short Ah[128 * 64];
  __shared__ __align__(16) unsigned short Al[128 * 64];
  __shared__ __align__(16) unsigned short Bh[128 * 64];
  __shared__ __align__(16) unsigned short Bl[128 * 64];
  const int tid = threadIdx.x;
  const int row0 = blockIdx.x * 128;
  const int col0 = blockIdx.y * 128;
  const int w = tid >> 6, lane = tid & 63, lg = lane >> 4, lc = lane & 15;
  const int wm = w >> 1, wn = w & 1;

  f32x4 acc[2][4];
#pragma unroll
  for (int i = 0; i < 2; ++i)
#pragma unroll
    for (int j = 0; j < 4; ++j) acc[i][j] = (f32x4){0.f, 0.f, 0.f, 0.f};

  for (int kc = 0; kc < 256; kc += 64) {
    __syncthreads();
#pragma unroll
    for (int l = 0; l < 2; ++l) {
      int idx = tid + l * 512;
      int r = idx >> 3, o = idx & 7;
      int sl = ((o ^ (r & 7))) * 8;
      *(uint4*)&Ah[r * 64 + sl] = *(const uint4*)&preh[(size_t)(row0 + r) * 256 + kc + o * 8];
      *(uint4*)&Al[r * 64 + sl] = *(const uint4*)&prel[(size_t)(row0 + r) * 256 + kc + o * 8];
      *(uint4*)&Bh[r * 64 + sl] = *(const uint4*)&pwhi[(size_t)(col0 + r) * 256 + kc + o * 8];
      *(uint4*)&Bl[r * 64 + sl] = *(const uint4*)&pwlo[(size_t)(col0 + r) * 256 + kc + o * 8];
    }
    __syncthreads();
#pragma unroll
    for (int ks = 0; ks < 2; ++ks) {
      short8 ah[2], al[2], bh[4], bl[4];
#pragma unroll
      for (int mi = 0; mi < 2; ++mi) {
        int r = wm * 32 + mi * 16 + lc;
        int sl = (((ks * 4 + lg) ^ (r & 7))) * 8;
        ah[mi] = *(short8*)&Ah[r * 64 + sl];
        al[mi] = *(short8*)&Al[r * 64 + sl];
      }
#pragma unroll
      for (int ni = 0; ni < 4; ++ni) {
        int r = wn * 64 + ni * 16 + lc;
        int sl = (((ks * 4 + lg) ^ (r & 7))) * 8;
        bh[ni] = *(short8*)&Bh[r * 64 + sl];
        bl[ni] = *(short8*)&Bl[r * 64 + sl];
      }
#pragma unroll
      for (int mi = 0; mi < 2; ++mi)
#pragma unroll
        for (int ni = 0; ni < 4; ++ni) {
          acc[mi][ni] = __builtin_amdgcn_mfma_f32_16x16x32_bf16(ah[mi], bh[ni], acc[mi][ni], 0, 0, 0);
          acc[mi][ni] = __builtin_amdgcn_mfma_f32_16x16x32_bf16(ah[mi], bl[ni], acc[mi][ni], 0, 0, 0);
          acc[mi][ni] = __builtin_amdgcn_mfma_f32_16x16x32_bf16(al[mi], bh[ni], acc[mi][ni], 0, 0, 0);
        }
    }
  }

#pragma unroll
  for (int mi = 0; mi < 2; ++mi) {
    int rbase = row0 + wm * 32 + mi * 16 + lg * 4;
#pragma unroll
    for (int ni = 0; ni < 4; ++ni) {
      int col = col0 + wn * 64 + ni * 16 + lc;
#pragma unroll
      for (int j = 0; j < 4; ++j)
        outp[(size_t)(rbase + j) * 256 + col] = acc[mi][ni][j] + bproj[col];
    }
  }
}

// ---------------------------------------------------------------------------
extern "C" void kernel_launch(void* const* d_in, const int* in_sizes, int n_in,
                              void* d_out, int out_size, void* d_ws, size_t ws_size,
                              hipStream_t stream) {
  const float* x     = (const float*)d_in[0];
  const float* wq    = (const float*)d_in[3];
  const float* wkv   = (const float*)d_in[4];
  const float* wres  = (const float*)d_in[5];
  const float* wproj = (const float*)d_in[6];
  const float* bproj = (const float*)d_in[7];
  const float* kern3 = (const float*)d_in[8];
  const float* kern5 = (const float*)d_in[9];
  const float* kern7 = (const float*)d_in[10];

  const size_t SZ = (size_t)4 * 8 * NTOK * 32;   // 2,359,296
  float* wsf  = (float*)d_ws;
  float* qb   = wsf;
  float* resb = wsf + SZ;
  float* accb = wsf + 2 * SZ;
  unsigned short* xhi = (unsigned short*)(wsf + 2 * SZ);
  unsigned short* xlo = (unsigned short*)(wsf + 2 * SZ + SZ / 2);
  unsigned short* khi = (unsigned short*)(wsf + 3 * SZ);
  unsigned short* klo = (unsigned short*)(wsf + 3 * SZ + SZ / 2);
  unsigned short* vT  = (unsigned short*)(wsf + 4 * SZ);
  unsigned short* resT = (unsigned short*)(wsf + 4 * SZ + SZ / 2);
  unsigned short* wT   = (unsigned short*)(wsf + 4 * SZ + SZ / 2 + 884736);
  unsigned short* Whi = (unsigned short*)(wsf + 4 * SZ + SZ / 2 + 884736 + 169984);
  unsigned short* Wlo = Whi + 262144;
  float* convb  = wsf + 3 * SZ;
  float* pooled = wsf + 4 * SZ;
  unsigned short* pwhi = (unsigned short*)(wsf + 4 * SZ + 40960);
  unsigned short* pwlo = pwhi + 65536;
  unsigned short* preh = (unsigned short*)(wsf + 4 * SZ + SZ / 2);
  unsigned short* prel = (unsigned short*)(wsf + 5 * SZ);
  float* outp = (float*)d_out;

  k_prep_x<<<dim3(2304), 256, 0, stream>>>(x, xhi, xlo);
  k_prep_w<<<dim3(256), 256, 0, stream>>>(wq, wkv, wres, Whi, Wlo);
  k_wprep<<<dim3(664), 512, 0, stream>>>(kern3, kern5, kern7, wT);
  k_gemm_qkvres_mfma<<<dim3(72, 8), 512, 0, stream>>>(xhi, xlo, Whi, Wlo, qb, khi,
                                                      klo, vT, resb, resT);
  k_attn_mfma<<<dim3(36, 32), 256, 0, stream>>>(qb, khi, klo, vT, accb);
  k_pool<1><<<dim3(256), 64, 0, stream>>>(resb, pooled);
  k_pool<2><<<dim3(256), 64, 0, stream>>>(resb, pooled);
  k_pool<3><<<dim3(256), 64, 0, stream>>>(resb, pooled);
  k_pool<6><<<dim3(256), 64, 0, stream>>>(resb, pooled);
  k_prep_wproj<<<dim3(64), 256, 0, stream>>>(wproj, pwhi, pwlo);
  k_conv_mfma<<<dim3(288), 512, 0, stream>>>(resT, wT, convb);
  k_combine<<<dim3(288, 8, 4), 256, 0, stream>>>(qb, accb, resb, convb, pooled,
                                                 preh, prel);
  k_gemm_proj_mfma<<<dim3(72, 2), 512, 0, stream>>>(preh, prel, pwhi, pwlo, bproj, outp);
}